// Round 15
// baseline (416.823 us; speedup 1.0000x reference)
//
#include <hip/hip_runtime.h>
#include <hip/hip_bf16.h>
#include <cmath>

#define C_DIM 96
#define RES_D 16
#define RES_H 56
#define RES_W 56
#define BATCH 4
#define SPATIAL (RES_D*RES_H*RES_W)      // 50176
#define NTOK (BATCH*SPATIAL)             // 200704
#define NWIN_TOT 2048
#define EPS_LN 1e-5f
#define QSCALE 0.2041241452319315f       // 1/sqrt(24)

#define MPAD 112        // window tokens padded 98 -> 112 (7 M-tiles, 7 waves)

// LDS layout (u16 element offsets) — head-PAIR buffers, 73.7KB -> 2 blocks/CU if regs fit
#define OFF_P   0              // [112][128]  P; later O overlay (own rows)
#define OFF_Q   14336          // [2][112][32] q pair-slabs
#define OFF_K   21504          // [2][112][32] k pair-slabs
#define OFF_VT  28672          // [2][32][128] v^T pair-slabs
#define SM_TOT  36864          // 73728 B

typedef float f32x4 __attribute__((ext_vector_type(4)));
typedef short s16x8 __attribute__((ext_vector_type(8)));
typedef unsigned u32x4 __attribute__((ext_vector_type(4)));
typedef unsigned u32x2 __attribute__((ext_vector_type(2)));
typedef unsigned short u16;

__device__ __forceinline__ u16 f2bf(float f) {
    unsigned u = __float_as_uint(f);
    u = (u + 0x7FFF + ((u >> 16) & 1)) >> 16;
    return (u16)u;
}
// packed pair bf16 convert (RNE, same rounding as f2bf)
__device__ __forceinline__ unsigned pk2(float lo, float hi) {
    return (unsigned)f2bf(lo) | ((unsigned)f2bf(hi) << 16);
}
// chunk-swizzled addressing: [r][128] bf16, 16B chunks XOR'd by row
__device__ __forceinline__ int swzP(int r, int c) {
    return r * 128 + ((((c >> 3) ^ (r & 15)) << 3) | (c & 7));
}
// [r][32] bf16 buffers (q/k)
__device__ __forceinline__ int swzQ(int r, int c) {
    return r * 32 + ((((c >> 3) ^ ((r >> 1) & 3)) << 3) | (c & 7));
}

__device__ __forceinline__ float wave_reduce_sum(float v) {
#pragma unroll
    for (int off = 32; off > 0; off >>= 1) v += __shfl_xor(v, off, 64);
    return v;
}

// ---------------- prep: bf16-transpose weights + dense rpb matrix ----------------
// rpbm[h][128][128] indexed [q-row][k-col]: k-pad (m>=98) = -30000; q-pad row = 0.
__global__ __launch_bounds__(256) void k_prep(
    const float* __restrict__ qkv_w, const float* __restrict__ proj_w,
    const float* __restrict__ fc1_w, const float* __restrict__ fc2_w,
    const float* __restrict__ rpb_table,
    u16* __restrict__ wq, u16* __restrict__ wp, u16* __restrict__ w1,
    u16* __restrict__ w2, float* __restrict__ rpbm) {
    int i = blockIdx.x * 256 + threadIdx.x;
    if (i < 27648) {
        int j = i / 96, c = i % 96;
        wq[i] = f2bf(qkv_w[c * 288 + j]);
    } else if (i < 36864) {
        int t = i - 27648; int j = t / 96, c = t % 96;
        wp[t] = f2bf(proj_w[c * 96 + j]);
    } else if (i < 73728) {
        int t = i - 36864; int j = t / 96, c = t % 96;
        w1[t] = f2bf(fc1_w[c * 384 + j]);
    } else if (i < 110592) {
        int t = i - 73728; int c = t / 384, j = t % 384;
        w2[t] = f2bf(fc2_w[j * 96 + c]);
    } else if (i < 176128) {
        int t = i - 110592;
        int h = t / 16384, r = t % 16384, n = r / 128, m = r % 128;
        float v;
        if (m >= 98) {
            v = -30000.0f;                 // k-col pad: exp -> 0
        } else if (n >= 98) {
            v = 0.0f;                      // q-pad row: harmless finite scores
        } else {
            int dzn = n / 49, rn = n % 49, hyn = rn / 7, wxn = rn % 7;
            int dzm = m / 49, rm = m % 49, hym = rm / 7, wxm = rm % 7;
            int ridx = (dzn - dzm + 1) * 169 + (hyn - hym + 6) * 13 + (wxn - wxm + 6);
            v = rpb_table[ridx * 4 + h];
        }
        rpbm[t] = v;
    }
}

// ---------------- (B,C,S) -> (B,S,C) transpose ----------------
__global__ __launch_bounds__(256) void k_transpose_in(const float* __restrict__ x,
                                                      float* __restrict__ xl) {
    __shared__ float tile[32][33];
    const int b = blockIdx.z;
    const int s0 = blockIdx.x * 32;
    const int c0 = blockIdx.y * 32;
    const float* xb = x + (size_t)b * C_DIM * SPATIAL;
    float* xlb = xl + (size_t)b * SPATIAL * C_DIM;
    const int ts = threadIdx.x, tc = threadIdx.y;
#pragma unroll
    for (int i = 0; i < 32; i += 8)
        tile[tc + i][ts] = xb[(size_t)(c0 + tc + i) * SPATIAL + s0 + ts];
    __syncthreads();
#pragma unroll
    for (int i = 0; i < 32; i += 8)
        xlb[(size_t)(s0 + tc + i) * C_DIM + c0 + ts] = tile[ts][tc + i];
}

// ---------------- per-window attention: token-major, head-pair phased (73.7KB LDS) ----------------
__global__ __launch_bounds__(448, 2) void k_win_attn(
    const float* __restrict__ xl, float* __restrict__ xl2,
    const float* __restrict__ g1, const float* __restrict__ b1,
    const u16* __restrict__ wqkv, const float* __restrict__ qkv_b,
    const u16* __restrict__ wproj, const float* __restrict__ proj_b,
    const float* __restrict__ rpbm) {
    __shared__ __align__(16) u16 sm[SM_TOT];
    __shared__ __align__(16) int s_gtok[MPAD];
    __shared__ __align__(16) int s_reg[MPAD];

    const int tid = threadIdx.x;
    const int lane = tid & 63;
    const int wv = tid >> 6;            // 0..6, owns M-tile wv
    const int g4 = lane >> 4;
    const int c16 = lane & 15;
    const int mt = wv;

    const int wid = blockIdx.x;
    const int b = wid >> 9;
    const int rem = wid & 511;
    const int wdi = rem >> 6, whi = (rem >> 3) & 7, wwi = rem & 7;

    // ---- targeted zeroing (pads only) ----
    for (int i = tid; i < 3584; i += 448) {            // q/k pad cols 24..31 (2 slabs each)
        int c = 24 + (i & 7);
        int slab = (i >> 3) / 112;                      // 0,1 -> q ; 2,3 -> k
        int r = (i >> 3) % 112;
        int base = (slab < 2) ? (OFF_Q + slab * 3584) : (OFF_K + (slab - 2) * 3584);
        sm[base + swzQ(r, c)] = 0;
    }
    for (int i = tid; i < 2048; i += 448) {            // vt pad d-rows 24..31 (2 slabs)
        int h = i >> 10, rr = 24 + ((i >> 7) & 7), c = i & 127;
        sm[OFF_VT + h * 4096 + swzP(rr, c)] = 0;
    }
    for (int i = tid; i < 768; i += 448) {             // vt tok-cols 112..127, d-rows 0..23
        int h = i / 384, r = (i % 384) >> 4, c = 112 + (i & 15);
        sm[OFF_VT + h * 4096 + swzP(r, c)] = 0;
    }
    for (int i = tid; i < 1792; i += 448) {            // P cols 112..127
        int r = i >> 4, c = 112 + (i & 15);
        sm[OFF_P + swzP(r, c)] = 0;
    }
    if (tid < MPAD) {
        if (tid < 98) {
            const int n = tid;
            const int dz = n / 49, r = n % 49, hy = r / 7, wx = r % 7;
            const int rd = wdi * 2 + dz, rh = whi * 7 + hy, rw = wwi * 7 + wx;
            int od = rd + 1; if (od >= RES_D) od -= RES_D;
            int oh = rh + 3; if (oh >= RES_H) oh -= RES_H;
            int ow = rw + 3; if (ow >= RES_W) ow -= RES_W;
            s_gtok[n] = ((b * RES_D + od) * RES_H + oh) * RES_W + ow;
            const int gd = (rd < 14) ? 0 : (rd < 15 ? 1 : 2);
            const int gh = (rh < 49) ? 0 : (rh < 53 ? 1 : 2);
            const int gw = (rw < 49) ? 0 : (rw < 53 ? 1 : 2);
            s_reg[n] = gd * 9 + gh * 3 + gw;
        } else { s_gtok[tid] = 0; s_reg[tid] = -1; }
    }
    __syncthreads();                                   // barrier 1 (gtok + pad zeros)

    const int mytok = mt * 16 + c16;                   // this lane's token row
    const float live = (mytok < 98) ? 1.0f : 0.0f;

    // ---- LN1 -> registers, fragment layout (row = mytok, cols ks*32+g4*8) ----
    u32x4 xa[3];
    {
        const float* src = xl + (size_t)s_gtok[mytok] * C_DIM;
        f32x4 xv0 = *(const f32x4*)(src + 0 * 32 + g4 * 8);
        f32x4 xv1 = *(const f32x4*)(src + 0 * 32 + g4 * 8 + 4);
        f32x4 xv2 = *(const f32x4*)(src + 1 * 32 + g4 * 8);
        f32x4 xv3 = *(const f32x4*)(src + 1 * 32 + g4 * 8 + 4);
        f32x4 xv4 = *(const f32x4*)(src + 2 * 32 + g4 * 8);
        f32x4 xv5 = *(const f32x4*)(src + 2 * 32 + g4 * 8 + 4);
        float lsum = (xv0[0]+xv0[1]+xv0[2]+xv0[3]) + (xv1[0]+xv1[1]+xv1[2]+xv1[3])
                   + (xv2[0]+xv2[1]+xv2[2]+xv2[3]) + (xv3[0]+xv3[1]+xv3[2]+xv3[3])
                   + (xv4[0]+xv4[1]+xv4[2]+xv4[3]) + (xv5[0]+xv5[1]+xv5[2]+xv5[3]);
        lsum += __shfl_xor(lsum, 16, 64);
        lsum += __shfl_xor(lsum, 32, 64);
        const float mu = lsum * (1.0f / 96.0f);
        f32x4 d0 = xv0 - mu, d1 = xv1 - mu, d2 = xv2 - mu,
              d3 = xv3 - mu, d4 = xv4 - mu, d5 = xv5 - mu;
        float lvv = (d0[0]*d0[0]+d0[1]*d0[1]+d0[2]*d0[2]+d0[3]*d0[3])
                  + (d1[0]*d1[0]+d1[1]*d1[1]+d1[2]*d1[2]+d1[3]*d1[3])
                  + (d2[0]*d2[0]+d2[1]*d2[1]+d2[2]*d2[2]+d2[3]*d2[3])
                  + (d3[0]*d3[0]+d3[1]*d3[1]+d3[2]*d3[2]+d3[3]*d3[3])
                  + (d4[0]*d4[0]+d4[1]*d4[1]+d4[2]*d4[2]+d4[3]*d4[3])
                  + (d5[0]*d5[0]+d5[1]*d5[1]+d5[2]*d5[2]+d5[3]*d5[3]);
        lvv += __shfl_xor(lvv, 16, 64);
        lvv += __shfl_xor(lvv, 32, 64);
        const float rstd = rsqrtf(lvv * (1.0f / 96.0f) + EPS_LN) * live;
#pragma unroll
        for (int ks = 0; ks < 3; ++ks) {
            const f32x4 ea = (ks == 0) ? d0 : (ks == 1) ? d2 : d4;
            const f32x4 eb = (ks == 0) ? d1 : (ks == 1) ? d3 : d5;
            f32x4 ga = *(const f32x4*)(g1 + ks * 32 + g4 * 8);
            f32x4 gb = *(const f32x4*)(g1 + ks * 32 + g4 * 8 + 4);
            f32x4 ba = *(const f32x4*)(b1 + ks * 32 + g4 * 8);
            f32x4 bb = *(const f32x4*)(b1 + ks * 32 + g4 * 8 + 4);
            f32x4 y0 = ea * rstd * ga + ba * live;
            f32x4 y1 = eb * rstd * gb + bb * live;
            xa[ks][0] = pk2(y0[0], y0[1]);
            xa[ks][1] = pk2(y0[2], y0[3]);
            xa[ks][2] = pk2(y1[0], y1[1]);
            xa[ks][3] = pk2(y1[2], y1[3]);
        }
    }

    // ---- shift-mask bits for this lane's 28 k-entries (bit nt*4+r) ----
    const int rgq = s_reg[mytok];
    unsigned mbits = 0;
#pragma unroll
    for (int nt = 0; nt < 7; ++nt) {
        const int4 cr = *(const int4*)&s_reg[nt * 16 + g4 * 4];
        mbits |= (unsigned)(cr.x != rgq) << (nt * 4 + 0);
        mbits |= (unsigned)(cr.y != rgq) << (nt * 4 + 1);
        mbits |= (unsigned)(cr.z != rgq) << (nt * 4 + 2);
        mbits |= (unsigned)(cr.w != rgq) << (nt * 4 + 3);
    }

    // ---- head pairs: QKV(pair) from registers -> attention(pair), token-major ----
    unsigned ogp[4][2][2];
#pragma unroll
    for (int p = 0; p < 2; ++p) {
        // QKV for this pair's 9 N-tiles
#pragma unroll
        for (int sel = 0; sel < 3; ++sel) {
#pragma unroll
            for (int t = 0; t < 3; ++t) {
                const int nt = sel * 6 + p * 3 + t;
                f32x4 acc = {0.f, 0.f, 0.f, 0.f};
                if (sel < 2) {
#pragma unroll
                    for (int ks = 0; ks < 3; ++ks) {
                        s16x8 bw = *(const s16x8*)(wqkv + (size_t)(nt * 16 + c16) * 96 + ks * 32 + g4 * 8);
                        acc = __builtin_amdgcn_mfma_f32_16x16x32_bf16(bw, __builtin_bit_cast(s16x8, xa[ks]), acc, 0, 0, 0);
                    }
                    const int lt = t * 16 + g4 * 4;    // 0..44 (4-aligned, never straddles 24)
                    const f32x4 b4 = *(const f32x4*)(qkv_b + sel * 96 + p * 48 + lt);
                    f32x4 v = acc + b4;
                    if (sel == 0) { v[0] *= QSCALE; v[1] *= QSCALE; v[2] *= QSCALE; v[3] *= QSCALE; }
                    const int hp = lt / 24, db = lt - hp * 24;
                    u32x2 pkv = { pk2(v[0], v[1]), pk2(v[2], v[3]) };
                    const int base = (sel == 0 ? OFF_Q : OFF_K) + hp * 3584;
                    *(u32x2*)&sm[base + swzQ(mytok, db)] = pkv;
                } else {
#pragma unroll
                    for (int ks = 0; ks < 3; ++ks) {
                        s16x8 bw = *(const s16x8*)(wqkv + (size_t)(nt * 16 + c16) * 96 + ks * 32 + g4 * 8);
                        acc = __builtin_amdgcn_mfma_f32_16x16x32_bf16(__builtin_bit_cast(s16x8, xa[ks]), bw, acc, 0, 0, 0);
                    }
                    const int lj = t * 16 + c16;       // 0..47
                    const float bias = qkv_b[192 + p * 48 + lj];
                    const int hp = lj / 24, d = lj - hp * 24;
                    const int row0 = mt * 16 + g4 * 4;
                    f32x4 v = acc + bias;
                    u32x2 pkv = { pk2(v[0], v[1]), pk2(v[2], v[3]) };
                    *(u32x2*)&sm[OFF_VT + hp * 4096 + swzP(d, row0)] = pkv;
                }
            }
        }
        __syncthreads();                               // pair QKV complete

#pragma unroll
        for (int hp = 0; hp < 2; ++hp) {
            const int h = p * 2 + hp;
            const s16x8 aq = *(const s16x8*)&sm[OFF_Q + hp * 3584 + swzQ(mytok, g4 * 8)];
            const float* rq = rpbm + h * 16384 + mytok * 128;
            float smr = 0.f;
#pragma unroll
            for (int nt = 0; nt < 7; ++nt) {
                s16x8 ak = *(const s16x8*)&sm[OFF_K + hp * 3584 + swzQ(nt * 16 + c16, g4 * 8)];
                f32x4 z = {0.f, 0.f, 0.f, 0.f};
                f32x4 sc = __builtin_amdgcn_mfma_f32_16x16x32_bf16(ak, aq, z, 0, 0, 0);  // swapped
                const f32x4 rv = *(const f32x4*)&rq[nt * 16 + g4 * 4];
                float s0 = sc[0] + rv[0] - 100.0f * (float)((mbits >> (nt * 4 + 0)) & 1u);
                float s1 = sc[1] + rv[1] - 100.0f * (float)((mbits >> (nt * 4 + 1)) & 1u);
                float s2 = sc[2] + rv[2] - 100.0f * (float)((mbits >> (nt * 4 + 2)) & 1u);
                float s3 = sc[3] + rv[3] - 100.0f * (float)((mbits >> (nt * 4 + 3)) & 1u);
                const float e0 = __expf(s0), e1 = __expf(s1), e2 = __expf(s2), e3 = __expf(s3);
                smr += (e0 + e1) + (e2 + e3);
                u32x2 pkv = { pk2(e0, e1), pk2(e2, e3) };
                *(u32x2*)&sm[OFF_P + swzP(mytok, nt * 16 + g4 * 4)] = pkv;
            }
            smr += __shfl_xor(smr, 16, 64);
            smr += __shfl_xor(smr, 32, 64);
            const float iq = 1.0f / fmaxf(smr, 1e-30f);
#pragma unroll
            for (int dt = 0; dt < 2; ++dt) {
                f32x4 acc = {0.f, 0.f, 0.f, 0.f};
#pragma unroll
                for (int ks = 0; ks < 4; ++ks) {
                    s16x8 av = *(const s16x8*)&sm[OFF_VT + hp * 4096 + swzP(dt * 16 + c16, ks * 32 + g4 * 8)];
                    s16x8 bp = *(const s16x8*)&sm[OFF_P + swzP(mt * 16 + c16, ks * 32 + g4 * 8)];
                    acc = __builtin_amdgcn_mfma_f32_16x16x32_bf16(av, bp, acc, 0, 0, 0);
                }
                ogp[h][dt][0] = pk2(acc[0] * iq, acc[1] * iq);
                ogp[h][dt][1] = pk2(acc[2] * iq, acc[3] * iq);
            }
        }
        if (p == 0) __syncthreads();                   // before pair-1 QKV overwrite
    }

    // ---- O -> P region (own token row, cols 0..95), vector stores; no barrier needed ----
#pragma unroll
    for (int h = 0; h < 4; ++h) {
#pragma unroll
        for (int dt = 0; dt < 2; ++dt) {
            const int db = dt * 16 + g4 * 4;
            if (db < 24) {
                u32x2 v = { ogp[h][dt][0], ogp[h][dt][1] };
                *(u32x2*)&sm[OFF_P + swzP(mytok, h * 24 + db)] = v;
            }
        }
    }

    // ---- proj (swapped) + residual -> xl2, vector f32x4 I/O (reads own P rows) ----
    const int gq = s_gtok[mytok];
#pragma unroll
    for (int nt = 0; nt < 6; ++nt) {
        f32x4 acc = {0.f, 0.f, 0.f, 0.f};
#pragma unroll
        for (int ks = 0; ks < 3; ++ks) {
            s16x8 aw = *(const s16x8*)(wproj + (size_t)(nt * 16 + c16) * 96 + ks * 32 + g4 * 8);
            s16x8 bo = *(const s16x8*)&sm[OFF_P + swzP(mt * 16 + c16, ks * 32 + g4 * 8)];
            acc = __builtin_amdgcn_mfma_f32_16x16x32_bf16(aw, bo, acc, 0, 0, 0);
        }
        if (mytok < 98) {
            const int cb = nt * 16 + g4 * 4;
            const f32x4 pb4 = *(const f32x4*)(proj_b + cb);
            const f32x4 res = *(const f32x4*)(xl + (size_t)gq * C_DIM + cb);
            *(f32x4*)(xl2 + (size_t)gq * C_DIM + cb) = acc + pb4 + res;
        }
    }
}

// ---------------- FFN v3 (unchanged from round 12/14, measured good) ----------------
__global__ __launch_bounds__(256, 3) void k_ffn(
    const float* __restrict__ xl2, float* __restrict__ out,
    const float* __restrict__ g2, const float* __restrict__ b2,
    const u16* __restrict__ w1, const float* __restrict__ fc1_b,
    const u16* __restrict__ w2, const float* __restrict__ fc2_b) {
    __shared__ __align__(16) u16 sg[64 * 384];   // 49152 B
    float* s_res = (float*)sg;                   // [64][97] f32, aliases sg

    const int tid = threadIdx.x;
    const int lane = tid & 63;
    const int wave = tid >> 6;
    const int g4 = lane >> 4, c16 = lane & 15;
    const int mg = wave & 1;
    const int nh = wave >> 1;
    const int t0 = blockIdx.x * 64;

    u32x4 xa[2][3];
#pragma unroll
    for (int g = 0; g < 2; ++g) {
        const int tok = mg * 32 + g * 16 + c16;
        const float* src = xl2 + (size_t)(t0 + tok) * C_DIM;
        f32x4 xv0 = *(const f32x4*)(src + 0 * 32 + g4 * 8);
        f32x4 xv1 = *(const f32x4*)(src + 0 * 32 + g4 * 8 + 4);
        f32x4 xv2 = *(const f32x4*)(src + 1 * 32 + g4 * 8);
        f32x4 xv3 = *(const f32x4*)(src + 1 * 32 + g4 * 8 + 4);
        f32x4 xv4 = *(const f32x4*)(src + 2 * 32 + g4 * 8);
        f32x4 xv5 = *(const f32x4*)(src + 2 * 32 + g4 * 8 + 4);
        float lsum = (xv0[0]+xv0[1]+xv0[2]+xv0[3]) + (xv1[0]+xv1[1]+xv1[2]+xv1[3])
                   + (xv2[0]+xv2[1]+xv2[2]+xv2[3]) + (xv3[0]+xv3[1]+xv3[2]+xv3[3])
                   + (xv4[0]+xv4[1]+xv4[2]+xv4[3]) + (xv5[0]+xv5[1]+xv5[2]+xv5[3]);
        lsum += __shfl_xor(lsum, 16, 64);
        lsum += __shfl_xor(lsum, 32, 64);
        const float mu = lsum * (1.0f / 96.0f);
        f32x4 d0 = xv0 - mu, d1 = xv1 - mu, d2 = xv2 - mu,
              d3 = xv3 - mu, d4 = xv4 - mu, d5 = xv5 - mu;
        float lvv = (d0[0]*d0[0]+d0[1]*d0[1]+d0[2]*d0[2]+d0[3]*d0[3])
                  + (d1[0]*d1[0]+d1[1]*d1[1]+d1[2]*d1[2]+d1[3]*d1[3])
                  + (d2[0]*d2[0]+d2[1]*d2[1]+d2[2]*d2[2]+d2[3]*d2[3])
                  + (d3[0]*d3[0]+d3[1]*d3[1]+d3[2]*d3[2]+d3[3]*d3[3])
                  + (d4[0]*d4[0]+d4[1]*d4[1]+d4[2]*d4[2]+d4[3]*d4[3])
                  + (d5[0]*d5[0]+d5[1]*d5[1]+d5[2]*d5[2]+d5[3]*d5[3]);
        lvv += __shfl_xor(lvv, 16, 64);
        lvv += __shfl_xor(lvv, 32, 64);
        const float rstd = rsqrtf(lvv * (1.0f / 96.0f) + EPS_LN);
#pragma unroll
        for (int ks = 0; ks < 3; ++ks) {
            const f32x4 ea = (ks == 0) ? d0 : (ks == 1) ? d2 : d4;
            const f32x4 eb = (ks == 0) ? d1 : (ks == 1) ? d3 : d5;
            f32x4 ga = *(const f32x4*)(g2 + ks * 32 + g4 * 8);
            f32x4 gb = *(const f32x4*)(g2 + ks * 32 + g4 * 8 + 4);
            f32x4 ba = *(const f32x4*)(b2 + ks * 32 + g4 * 8);
            f32x4 bb = *(const f32x4*)(b2 + ks * 32 + g4 * 8 + 4);
            f32x4 y0 = ea * rstd * ga + ba;
            f32x4 y1 = eb * rstd * gb + bb;
            xa[g][ks][0] = pk2(y0[0], y0[1]);
            xa[g][ks][1] = pk2(y0[2], y0[3]);
            xa[g][ks][2] = pk2(y1[0], y1[1]);
            xa[g][ks][3] = pk2(y1[2], y1[3]);
        }
    }

#pragma unroll 1
    for (int i = 0; i < 12; ++i) {
        const int nt = nh * 12 + i;
        f32x4 acc0 = {0.f, 0.f, 0.f, 0.f};
        f32x4 acc1 = {0.f, 0.f, 0.f, 0.f};
#pragma unroll
        for (int ks = 0; ks < 3; ++ks) {
            s16x8 aw = *(const s16x8*)(w1 + (size_t)(nt * 16 + c16) * 96 + ks * 32 + g4 * 8);
            acc0 = __builtin_amdgcn_mfma_f32_16x16x32_bf16(aw, __builtin_bit_cast(s16x8, xa[0][ks]), acc0, 0, 0, 0);
            acc1 = __builtin_amdgcn_mfma_f32_16x16x32_bf16(aw, __builtin_bit_cast(s16x8, xa[1][ks]), acc1, 0, 0, 0);
        }
        const f32x4 bias = *(const f32x4*)(fc1_b + nt * 16 + g4 * 4);
#pragma unroll
        for (int g = 0; g < 2; ++g) {
            const f32x4 acc = (g == 0) ? acc0 : acc1;
            const int tok = mg * 32 + g * 16 + c16;
            float gv[4];
#pragma unroll
            for (int r = 0; r < 4; ++r) {
                const float v = acc[r] + bias[r];
                gv[r] = 0.5f * v * (1.0f + erff(v * 0.70710678118654752f));
            }
            const int chunk = (2 * nt + (g4 >> 1)) ^ (tok & 15);
            u32x2 pk = { pk2(gv[0], gv[1]), pk2(gv[2], gv[3]) };
            *(u32x2*)&sg[tok * 384 + chunk * 8 + (g4 & 1) * 4] = pk;
        }
    }
    __syncthreads();

    f32x4 facc[3][2];
    const int tokA = mg * 32 + c16;
    const int tokB = tokA + 16;
#pragma unroll 1
    for (int i = 0; i < 3; ++i) {
        const int nt = nh * 3 + i;
        f32x4 a0 = {0.f, 0.f, 0.f, 0.f};
        f32x4 a1 = {0.f, 0.f, 0.f, 0.f};
#pragma unroll
        for (int ks = 0; ks < 12; ++ks) {
            s16x8 aw = *(const s16x8*)(w2 + (size_t)(nt * 16 + c16) * 384 + ks * 32 + g4 * 8);
            s16x8 bg0 = *(const s16x8*)&sg[tokA * 384 + (((ks * 4 + g4) ^ (tokA & 15)) << 3)];
            s16x8 bg1 = *(const s16x8*)&sg[tokB * 384 + (((ks * 4 + g4) ^ (tokB & 15)) << 3)];
            a0 = __builtin_amdgcn_mfma_f32_16x16x32_bf16(aw, bg0, a0, 0, 0, 0);
            a1 = __builtin_amdgcn_mfma_f32_16x16x32_bf16(aw, bg1, a1, 0, 0, 0);
        }
        const f32x4 bias = *(const f32x4*)(fc2_b + nt * 16 + g4 * 4);
        const f32x4 resA = *(const f32x4*)(xl2 + (size_t)(t0 + tokA) * C_DIM + nt * 16 + g4 * 4);
        const f32x4 resB = *(const f32x4*)(xl2 + (size_t)(t0 + tokB) * C_DIM + nt * 16 + g4 * 4);
        facc[i][0] = a0 + bias + resA;
        facc[i][1] = a1 + bias + resB;
    }
    __syncthreads();

#pragma unroll
    for (int i = 0; i < 3; ++i) {
        const int nt = nh * 3 + i;
#pragma unroll
        for (int g = 0; g < 2; ++g) {
            const int tok = mg * 32 + g * 16 + c16;
#pragma unroll
            for (int r = 0; r < 4; ++r)
                s_res[tok * 97 + nt * 16 + g4 * 4 + r] = facc[i][g][r];
        }
    }
    __syncthreads();

    const int bb = t0 / SPATIAL;
    const int sbase = t0 % SPATIAL;
    for (int e = tid; e < 1536; e += 256) {
        const int c = e >> 4, tq = e & 15;
        f32x4 v;
        v[0] = s_res[(tq * 4 + 0) * 97 + c];
        v[1] = s_res[(tq * 4 + 1) * 97 + c];
        v[2] = s_res[(tq * 4 + 2) * 97 + c];
        v[3] = s_res[(tq * 4 + 3) * 97 + c];
        *(f32x4*)&out[((size_t)bb * C_DIM + c) * SPATIAL + sbase + tq * 4] = v;
    }
}

extern "C" void kernel_launch(void* const* d_in, const int* in_sizes, int n_in,
                              void* d_out, int out_size, void* d_ws, size_t ws_size,
                              hipStream_t stream) {
    const float* x      = (const float*)d_in[0];
    const float* g1     = (const float*)d_in[1];
    const float* be1    = (const float*)d_in[2];
    const float* g2     = (const float*)d_in[3];
    const float* be2    = (const float*)d_in[4];
    const float* qkv_w  = (const float*)d_in[5];
    const float* qkv_b  = (const float*)d_in[6];
    const float* proj_w = (const float*)d_in[7];
    const float* proj_b = (const float*)d_in[8];
    const float* rpb    = (const float*)d_in[9];
    const float* fc1_w  = (const float*)d_in[10];
    const float* fc1_b  = (const float*)d_in[11];
    const float* fc2_w  = (const float*)d_in[12];
    const float* fc2_b  = (const float*)d_in[13];
    float* out = (float*)d_out;

    float* xl  = (float*)d_ws;
    float* xl2 = xl + (size_t)NTOK * C_DIM;
    u16* wq = (u16*)(xl2 + (size_t)NTOK * C_DIM);
    u16* wp = wq + 27648;
    u16* w1 = wp + 9216;
    u16* w2 = w1 + 36864;
    float* rpbm = (float*)(w2 + 36864);

    k_prep<<<688, 256, 0, stream>>>(qkv_w, proj_w, fc1_w, fc2_w, rpb, wq, wp, w1, w2, rpbm);
    k_transpose_in<<<dim3(SPATIAL / 32, C_DIM / 32, BATCH), dim3(32, 8), 0, stream>>>(x, xl);
    k_win_attn<<<NWIN_TOT, 448, 0, stream>>>(xl, xl2, g1, be1, wq, qkv_b, wp, proj_b, rpbm);
    k_ffn<<<NTOK / 64, 256, 0, stream>>>(xl2, out, g2, be2, w1, fc1_b, w2, fc2_b);
}

// Round 16
// 383.136 us; speedup vs baseline: 1.0879x; 1.0879x over previous
//
#include <hip/hip_runtime.h>
#include <hip/hip_bf16.h>
#include <cmath>

#define C_DIM 96
#define RES_D 16
#define RES_H 56
#define RES_W 56
#define BATCH 4
#define SPATIAL (RES_D*RES_H*RES_W)      // 50176
#define NTOK (BATCH*SPATIAL)             // 200704
#define NWIN_TOT 2048
#define EPS_LN 1e-5f
#define QSCALE 0.2041241452319315f       // 1/sqrt(24)

#define MPAD 112        // window tokens padded 98 -> 112 (7 M-tiles, 7 waves)

// LDS layout (u16 element offsets) — full 4-head buffers, 1 block/CU by design
#define OFF_P   0              // [112][128]  P; later O overlay (own rows)
#define OFF_Q   14336          // [4][112][32] q head-slabs
#define OFF_K   28672          // [4][112][32] k head-slabs
#define OFF_VT  43008          // [4][32][128] v^T head-slabs
#define SM_TOT  59392          // 118784 B

typedef float f32x4 __attribute__((ext_vector_type(4)));
typedef short s16x8 __attribute__((ext_vector_type(8)));
typedef unsigned u32x4 __attribute__((ext_vector_type(4)));
typedef unsigned u32x2 __attribute__((ext_vector_type(2)));
typedef unsigned short u16;

__device__ __forceinline__ u16 f2bf(float f) {
    unsigned u = __float_as_uint(f);
    u = (u + 0x7FFF + ((u >> 16) & 1)) >> 16;
    return (u16)u;
}
// packed pair bf16 convert (RNE, same rounding as f2bf)
__device__ __forceinline__ unsigned pk2(float lo, float hi) {
    return (unsigned)f2bf(lo) | ((unsigned)f2bf(hi) << 16);
}
// chunk-swizzled addressing: [r][128] bf16, 16B chunks XOR'd by row
__device__ __forceinline__ int swzP(int r, int c) {
    return r * 128 + ((((c >> 3) ^ (r & 15)) << 3) | (c & 7));
}
// [r][32] bf16 buffers (q/k)
__device__ __forceinline__ int swzQ(int r, int c) {
    return r * 32 + ((((c >> 3) ^ ((r >> 1) & 3)) << 3) | (c & 7));
}

__device__ __forceinline__ float wave_reduce_sum(float v) {
#pragma unroll
    for (int off = 32; off > 0; off >>= 1) v += __shfl_xor(v, off, 64);
    return v;
}

// ---------------- prep: bf16-transpose weights + dense rpb matrix ----------------
// rpbm[h][128][128] indexed [q-row][k-col]: k-pad (m>=98) = -30000; q-pad row = 0.
__global__ __launch_bounds__(256) void k_prep(
    const float* __restrict__ qkv_w, const float* __restrict__ proj_w,
    const float* __restrict__ fc1_w, const float* __restrict__ fc2_w,
    const float* __restrict__ rpb_table,
    u16* __restrict__ wq, u16* __restrict__ wp, u16* __restrict__ w1,
    u16* __restrict__ w2, float* __restrict__ rpbm) {
    int i = blockIdx.x * 256 + threadIdx.x;
    if (i < 27648) {
        int j = i / 96, c = i % 96;
        wq[i] = f2bf(qkv_w[c * 288 + j]);
    } else if (i < 36864) {
        int t = i - 27648; int j = t / 96, c = t % 96;
        wp[t] = f2bf(proj_w[c * 96 + j]);
    } else if (i < 73728) {
        int t = i - 36864; int j = t / 96, c = t % 96;
        w1[t] = f2bf(fc1_w[c * 384 + j]);
    } else if (i < 110592) {
        int t = i - 73728; int c = t / 384, j = t % 384;
        w2[t] = f2bf(fc2_w[j * 96 + c]);
    } else if (i < 176128) {
        int t = i - 110592;
        int h = t / 16384, r = t % 16384, n = r / 128, m = r % 128;
        float v;
        if (m >= 98) {
            v = -30000.0f;                 // k-col pad: exp -> 0
        } else if (n >= 98) {
            v = 0.0f;                      // q-pad row: harmless finite scores
        } else {
            int dzn = n / 49, rn = n % 49, hyn = rn / 7, wxn = rn % 7;
            int dzm = m / 49, rm = m % 49, hym = rm / 7, wxm = rm % 7;
            int ridx = (dzn - dzm + 1) * 169 + (hyn - hym + 6) * 13 + (wxn - wxm + 6);
            v = rpb_table[ridx * 4 + h];
        }
        rpbm[t] = v;
    }
}

// ---------------- (B,C,S) -> (B,S,C) transpose ----------------
__global__ __launch_bounds__(256) void k_transpose_in(const float* __restrict__ x,
                                                      float* __restrict__ xl) {
    __shared__ float tile[32][33];
    const int b = blockIdx.z;
    const int s0 = blockIdx.x * 32;
    const int c0 = blockIdx.y * 32;
    const float* xb = x + (size_t)b * C_DIM * SPATIAL;
    float* xlb = xl + (size_t)b * SPATIAL * C_DIM;
    const int ts = threadIdx.x, tc = threadIdx.y;
#pragma unroll
    for (int i = 0; i < 32; i += 8)
        tile[tc + i][ts] = xb[(size_t)(c0 + tc + i) * SPATIAL + s0 + ts];
    __syncthreads();
#pragma unroll
    for (int i = 0; i < 32; i += 8)
        xlb[(size_t)(s0 + tc + i) * C_DIM + c0 + ts] = tile[ts][tc + i];
}

// ---------------- per-window attention: token-major, 4-head barrier-free (R14) + setprio ----------------
__global__ __launch_bounds__(448, 2) void k_win_attn(
    const float* __restrict__ xl, float* __restrict__ xl2,
    const float* __restrict__ g1, const float* __restrict__ b1,
    const u16* __restrict__ wqkv, const float* __restrict__ qkv_b,
    const u16* __restrict__ wproj, const float* __restrict__ proj_b,
    const float* __restrict__ rpbm) {
    __shared__ __align__(16) u16 sm[SM_TOT];
    __shared__ __align__(16) int s_gtok[MPAD];
    __shared__ __align__(16) int s_reg[MPAD];

    const int tid = threadIdx.x;
    const int lane = tid & 63;
    const int wv = tid >> 6;            // 0..6, owns M-tile wv
    const int g4 = lane >> 4;
    const int c16 = lane & 15;
    const int mt = wv;

    const int wid = blockIdx.x;
    const int b = wid >> 9;
    const int rem = wid & 511;
    const int wdi = rem >> 6, whi = (rem >> 3) & 7, wwi = rem & 7;

    // ---- targeted zeroing (pads only) ----
    for (int i = tid; i < 7168; i += 448) {            // q/k pad cols 24..31, 4 slabs each
        int c = 24 + (i & 7);
        int hb = (i >> 3) / 112;                        // 0..7
        int r = (i >> 3) % 112;
        int base = (hb < 4) ? (OFF_Q + hb * 3584) : (OFF_K + (hb - 4) * 3584);
        sm[base + swzQ(r, c)] = 0;
    }
    for (int i = tid; i < 4096; i += 448) {            // vt pad d-rows 24..31 (all cols)
        int h = i >> 10, rr = 24 + ((i >> 7) & 7), c = i & 127;
        sm[OFF_VT + h * 4096 + swzP(rr, c)] = 0;
    }
    for (int i = tid; i < 1536; i += 448) {            // vt tok-cols 112..127, d-rows 0..23
        int h = i / 384, r = (i % 384) >> 4, c = 112 + (i & 15);
        sm[OFF_VT + h * 4096 + swzP(r, c)] = 0;
    }
    for (int i = tid; i < 1792; i += 448) {            // P cols 112..127
        int r = i >> 4, c = 112 + (i & 15);
        sm[OFF_P + swzP(r, c)] = 0;
    }
    if (tid < MPAD) {
        if (tid < 98) {
            const int n = tid;
            const int dz = n / 49, r = n % 49, hy = r / 7, wx = r % 7;
            const int rd = wdi * 2 + dz, rh = whi * 7 + hy, rw = wwi * 7 + wx;
            int od = rd + 1; if (od >= RES_D) od -= RES_D;
            int oh = rh + 3; if (oh >= RES_H) oh -= RES_H;
            int ow = rw + 3; if (ow >= RES_W) ow -= RES_W;
            s_gtok[n] = ((b * RES_D + od) * RES_H + oh) * RES_W + ow;
            const int gd = (rd < 14) ? 0 : (rd < 15 ? 1 : 2);
            const int gh = (rh < 49) ? 0 : (rh < 53 ? 1 : 2);
            const int gw = (rw < 49) ? 0 : (rw < 53 ? 1 : 2);
            s_reg[n] = gd * 9 + gh * 3 + gw;
        } else { s_gtok[tid] = 0; s_reg[tid] = -1; }
    }
    __syncthreads();                                   // barrier 1 (gtok + pad zeros)

    const int mytok = mt * 16 + c16;                   // this lane's token row
    const float live = (mytok < 98) ? 1.0f : 0.0f;

    // ---- LN1 -> registers, fragment layout (row = mytok, cols ks*32+g4*8) ----
    u32x4 xa[3];
    {
        const float* src = xl + (size_t)s_gtok[mytok] * C_DIM;
        f32x4 xv0 = *(const f32x4*)(src + 0 * 32 + g4 * 8);
        f32x4 xv1 = *(const f32x4*)(src + 0 * 32 + g4 * 8 + 4);
        f32x4 xv2 = *(const f32x4*)(src + 1 * 32 + g4 * 8);
        f32x4 xv3 = *(const f32x4*)(src + 1 * 32 + g4 * 8 + 4);
        f32x4 xv4 = *(const f32x4*)(src + 2 * 32 + g4 * 8);
        f32x4 xv5 = *(const f32x4*)(src + 2 * 32 + g4 * 8 + 4);
        float lsum = (xv0[0]+xv0[1]+xv0[2]+xv0[3]) + (xv1[0]+xv1[1]+xv1[2]+xv1[3])
                   + (xv2[0]+xv2[1]+xv2[2]+xv2[3]) + (xv3[0]+xv3[1]+xv3[2]+xv3[3])
                   + (xv4[0]+xv4[1]+xv4[2]+xv4[3]) + (xv5[0]+xv5[1]+xv5[2]+xv5[3]);
        lsum += __shfl_xor(lsum, 16, 64);
        lsum += __shfl_xor(lsum, 32, 64);
        const float mu = lsum * (1.0f / 96.0f);
        f32x4 d0 = xv0 - mu, d1 = xv1 - mu, d2 = xv2 - mu,
              d3 = xv3 - mu, d4 = xv4 - mu, d5 = xv5 - mu;
        float lvv = (d0[0]*d0[0]+d0[1]*d0[1]+d0[2]*d0[2]+d0[3]*d0[3])
                  + (d1[0]*d1[0]+d1[1]*d1[1]+d1[2]*d1[2]+d1[3]*d1[3])
                  + (d2[0]*d2[0]+d2[1]*d2[1]+d2[2]*d2[2]+d2[3]*d2[3])
                  + (d3[0]*d3[0]+d3[1]*d3[1]+d3[2]*d3[2]+d3[3]*d3[3])
                  + (d4[0]*d4[0]+d4[1]*d4[1]+d4[2]*d4[2]+d4[3]*d4[3])
                  + (d5[0]*d5[0]+d5[1]*d5[1]+d5[2]*d5[2]+d5[3]*d5[3]);
        lvv += __shfl_xor(lvv, 16, 64);
        lvv += __shfl_xor(lvv, 32, 64);
        const float rstd = rsqrtf(lvv * (1.0f / 96.0f) + EPS_LN) * live;
#pragma unroll
        for (int ks = 0; ks < 3; ++ks) {
            const f32x4 ea = (ks == 0) ? d0 : (ks == 1) ? d2 : d4;
            const f32x4 eb = (ks == 0) ? d1 : (ks == 1) ? d3 : d5;
            f32x4 ga = *(const f32x4*)(g1 + ks * 32 + g4 * 8);
            f32x4 gb = *(const f32x4*)(g1 + ks * 32 + g4 * 8 + 4);
            f32x4 ba = *(const f32x4*)(b1 + ks * 32 + g4 * 8);
            f32x4 bb = *(const f32x4*)(b1 + ks * 32 + g4 * 8 + 4);
            f32x4 y0 = ea * rstd * ga + ba * live;
            f32x4 y1 = eb * rstd * gb + bb * live;
            xa[ks][0] = pk2(y0[0], y0[1]);
            xa[ks][1] = pk2(y0[2], y0[3]);
            xa[ks][2] = pk2(y1[0], y1[1]);
            xa[ks][3] = pk2(y1[2], y1[3]);
        }
    }

    // ---- QKV: q,k swapped (vector stores); v original (vector token-run stores) ----
#pragma unroll
    for (int sel = 0; sel < 3; ++sel) {
#pragma unroll
        for (int t = 0; t < 6; ++t) {
            const int nt = sel * 6 + t;
            f32x4 acc = {0.f, 0.f, 0.f, 0.f};
            if (sel < 2) {
#pragma unroll
                for (int ks = 0; ks < 3; ++ks) {
                    s16x8 bw = *(const s16x8*)(wqkv + (size_t)(nt * 16 + c16) * 96 + ks * 32 + g4 * 8);
                    acc = __builtin_amdgcn_mfma_f32_16x16x32_bf16(bw, __builtin_bit_cast(s16x8, xa[ks]), acc, 0, 0, 0);
                }
                const int jb = t * 16 + g4 * 4;        // 0..92, 4-run never straddles a head
                const f32x4 b4 = *(const f32x4*)(qkv_b + sel * 96 + jb);
                f32x4 v = acc + b4;
                if (sel == 0) { v[0] *= QSCALE; v[1] *= QSCALE; v[2] *= QSCALE; v[3] *= QSCALE; }
                const int h = jb / 24, db = jb - h * 24;
                u32x2 pkv = { pk2(v[0], v[1]), pk2(v[2], v[3]) };
                const int base = (sel == 0 ? OFF_Q : OFF_K) + h * 3584;
                *(u32x2*)&sm[base + swzQ(mytok, db)] = pkv;
            } else {
#pragma unroll
                for (int ks = 0; ks < 3; ++ks) {
                    s16x8 bw = *(const s16x8*)(wqkv + (size_t)(nt * 16 + c16) * 96 + ks * 32 + g4 * 8);
                    acc = __builtin_amdgcn_mfma_f32_16x16x32_bf16(__builtin_bit_cast(s16x8, xa[ks]), bw, acc, 0, 0, 0);
                }
                const int j96 = t * 16 + c16;
                const float bias = qkv_b[192 + j96];
                const int h = j96 / 24, d = j96 - h * 24;
                const int row0 = mt * 16 + g4 * 4;
                f32x4 v = acc + bias;
                u32x2 pkv = { pk2(v[0], v[1]), pk2(v[2], v[3]) };
                *(u32x2*)&sm[OFF_VT + h * 4096 + swzP(d, row0)] = pkv;
            }
        }
    }
    __syncthreads();                                   // barrier 2 (q/k/vt complete)

    // ---- shift-mask bits for this lane's 28 k-entries (bit nt*4+r) ----
    const int rgq = s_reg[mytok];
    unsigned mbits = 0;
#pragma unroll
    for (int nt = 0; nt < 7; ++nt) {
        const int4 cr = *(const int4*)&s_reg[nt * 16 + g4 * 4];
        mbits |= (unsigned)(cr.x != rgq) << (nt * 4 + 0);
        mbits |= (unsigned)(cr.y != rgq) << (nt * 4 + 1);
        mbits |= (unsigned)(cr.z != rgq) << (nt * 4 + 2);
        mbits |= (unsigned)(cr.w != rgq) << (nt * 4 + 3);
    }

    // ---- 4 heads, barrier-free, token-major; setprio(1) around MFMA clusters (T5) ----
    unsigned ogp[4][2][2];
#pragma unroll
    for (int h = 0; h < 4; ++h) {
        const s16x8 aq = *(const s16x8*)&sm[OFF_Q + h * 3584 + swzQ(mytok, g4 * 8)];
        const float* rq = rpbm + h * 16384 + mytok * 128;
        float smr = 0.f;
#pragma unroll
        for (int nt = 0; nt < 7; ++nt) {
            s16x8 ak = *(const s16x8*)&sm[OFF_K + h * 3584 + swzQ(nt * 16 + c16, g4 * 8)];
            f32x4 z = {0.f, 0.f, 0.f, 0.f};
            __builtin_amdgcn_s_setprio(1);
            f32x4 sc = __builtin_amdgcn_mfma_f32_16x16x32_bf16(ak, aq, z, 0, 0, 0);  // swapped: row=k, col=q
            __builtin_amdgcn_s_setprio(0);
            const f32x4 rv = *(const f32x4*)&rq[nt * 16 + g4 * 4];
            float s0 = sc[0] + rv[0] - 100.0f * (float)((mbits >> (nt * 4 + 0)) & 1u);
            float s1 = sc[1] + rv[1] - 100.0f * (float)((mbits >> (nt * 4 + 1)) & 1u);
            float s2 = sc[2] + rv[2] - 100.0f * (float)((mbits >> (nt * 4 + 2)) & 1u);
            float s3 = sc[3] + rv[3] - 100.0f * (float)((mbits >> (nt * 4 + 3)) & 1u);
            const float e0 = __expf(s0), e1 = __expf(s1), e2 = __expf(s2), e3 = __expf(s3);
            smr += (e0 + e1) + (e2 + e3);
            u32x2 pkv = { pk2(e0, e1), pk2(e2, e3) };
            *(u32x2*)&sm[OFF_P + swzP(mytok, nt * 16 + g4 * 4)] = pkv;
        }
        smr += __shfl_xor(smr, 16, 64);
        smr += __shfl_xor(smr, 32, 64);
        const float iq = 1.0f / fmaxf(smr, 1e-30f);
        // PV swapped: A=VT (rows=d), B=P (cols=q tokens) -> lane holds 4 d of own token
        __builtin_amdgcn_s_setprio(1);
#pragma unroll
        for (int dt = 0; dt < 2; ++dt) {
            f32x4 acc = {0.f, 0.f, 0.f, 0.f};
#pragma unroll
            for (int ks = 0; ks < 4; ++ks) {
                s16x8 av = *(const s16x8*)&sm[OFF_VT + h * 4096 + swzP(dt * 16 + c16, ks * 32 + g4 * 8)];
                s16x8 bp = *(const s16x8*)&sm[OFF_P + swzP(mt * 16 + c16, ks * 32 + g4 * 8)];
                acc = __builtin_amdgcn_mfma_f32_16x16x32_bf16(av, bp, acc, 0, 0, 0);
            }
            ogp[h][dt][0] = pk2(acc[0] * iq, acc[1] * iq);
            ogp[h][dt][1] = pk2(acc[2] * iq, acc[3] * iq);
        }
        __builtin_amdgcn_s_setprio(0);
    }

    // ---- O -> P region (own token row, cols 0..95), vector stores ----
#pragma unroll
    for (int h = 0; h < 4; ++h) {
#pragma unroll
        for (int dt = 0; dt < 2; ++dt) {
            const int db = dt * 16 + g4 * 4;
            if (db < 24) {
                u32x2 v = { ogp[h][dt][0], ogp[h][dt][1] };
                *(u32x2*)&sm[OFF_P + swzP(mytok, h * 24 + db)] = v;
            }
        }
    }

    // ---- proj (swapped) + residual -> xl2, vector f32x4 I/O ----
    const int gq = s_gtok[mytok];
#pragma unroll
    for (int nt = 0; nt < 6; ++nt) {
        f32x4 acc = {0.f, 0.f, 0.f, 0.f};
#pragma unroll
        for (int ks = 0; ks < 3; ++ks) {
            s16x8 aw = *(const s16x8*)(wproj + (size_t)(nt * 16 + c16) * 96 + ks * 32 + g4 * 8);
            s16x8 bo = *(const s16x8*)&sm[OFF_P + swzP(mt * 16 + c16, ks * 32 + g4 * 8)];
            acc = __builtin_amdgcn_mfma_f32_16x16x32_bf16(aw, bo, acc, 0, 0, 0);
        }
        if (mytok < 98) {
            const int cb = nt * 16 + g4 * 4;
            const f32x4 pb4 = *(const f32x4*)(proj_b + cb);
            const f32x4 res = *(const f32x4*)(xl + (size_t)gq * C_DIM + cb);
            *(f32x4*)(xl2 + (size_t)gq * C_DIM + cb) = acc + pb4 + res;
        }
    }
}

// ---------------- FFN v3 (unchanged from round 12/14, measured good) ----------------
__global__ __launch_bounds__(256, 3) void k_ffn(
    const float* __restrict__ xl2, float* __restrict__ out,
    const float* __restrict__ g2, const float* __restrict__ b2,
    const u16* __restrict__ w1, const float* __restrict__ fc1_b,
    const u16* __restrict__ w2, const float* __restrict__ fc2_b) {
    __shared__ __align__(16) u16 sg[64 * 384];   // 49152 B
    float* s_res = (float*)sg;                   // [64][97] f32, aliases sg

    const int tid = threadIdx.x;
    const int lane = tid & 63;
    const int wave = tid >> 6;
    const int g4 = lane >> 4, c16 = lane & 15;
    const int mg = wave & 1;
    const int nh = wave >> 1;
    const int t0 = blockIdx.x * 64;

    u32x4 xa[2][3];
#pragma unroll
    for (int g = 0; g < 2; ++g) {
        const int tok = mg * 32 + g * 16 + c16;
        const float* src = xl2 + (size_t)(t0 + tok) * C_DIM;
        f32x4 xv0 = *(const f32x4*)(src + 0 * 32 + g4 * 8);
        f32x4 xv1 = *(const f32x4*)(src + 0 * 32 + g4 * 8 + 4);
        f32x4 xv2 = *(const f32x4*)(src + 1 * 32 + g4 * 8);
        f32x4 xv3 = *(const f32x4*)(src + 1 * 32 + g4 * 8 + 4);
        f32x4 xv4 = *(const f32x4*)(src + 2 * 32 + g4 * 8);
        f32x4 xv5 = *(const f32x4*)(src + 2 * 32 + g4 * 8 + 4);
        float lsum = (xv0[0]+xv0[1]+xv0[2]+xv0[3]) + (xv1[0]+xv1[1]+xv1[2]+xv1[3])
                   + (xv2[0]+xv2[1]+xv2[2]+xv2[3]) + (xv3[0]+xv3[1]+xv3[2]+xv3[3])
                   + (xv4[0]+xv4[1]+xv4[2]+xv4[3]) + (xv5[0]+xv5[1]+xv5[2]+xv5[3]);
        lsum += __shfl_xor(lsum, 16, 64);
        lsum += __shfl_xor(lsum, 32, 64);
        const float mu = lsum * (1.0f / 96.0f);
        f32x4 d0 = xv0 - mu, d1 = xv1 - mu, d2 = xv2 - mu,
              d3 = xv3 - mu, d4 = xv4 - mu, d5 = xv5 - mu;
        float lvv = (d0[0]*d0[0]+d0[1]*d0[1]+d0[2]*d0[2]+d0[3]*d0[3])
                  + (d1[0]*d1[0]+d1[1]*d1[1]+d1[2]*d1[2]+d1[3]*d1[3])
                  + (d2[0]*d2[0]+d2[1]*d2[1]+d2[2]*d2[2]+d2[3]*d2[3])
                  + (d3[0]*d3[0]+d3[1]*d3[1]+d3[2]*d3[2]+d3[3]*d3[3])
                  + (d4[0]*d4[0]+d4[1]*d4[1]+d4[2]*d4[2]+d4[3]*d4[3])
                  + (d5[0]*d5[0]+d5[1]*d5[1]+d5[2]*d5[2]+d5[3]*d5[3]);
        lvv += __shfl_xor(lvv, 16, 64);
        lvv += __shfl_xor(lvv, 32, 64);
        const float rstd = rsqrtf(lvv * (1.0f / 96.0f) + EPS_LN);
#pragma unroll
        for (int ks = 0; ks < 3; ++ks) {
            const f32x4 ea = (ks == 0) ? d0 : (ks == 1) ? d2 : d4;
            const f32x4 eb = (ks == 0) ? d1 : (ks == 1) ? d3 : d5;
            f32x4 ga = *(const f32x4*)(g2 + ks * 32 + g4 * 8);
            f32x4 gb = *(const f32x4*)(g2 + ks * 32 + g4 * 8 + 4);
            f32x4 ba = *(const f32x4*)(b2 + ks * 32 + g4 * 8);
            f32x4 bb = *(const f32x4*)(b2 + ks * 32 + g4 * 8 + 4);
            f32x4 y0 = ea * rstd * ga + ba;
            f32x4 y1 = eb * rstd * gb + bb;
            xa[g][ks][0] = pk2(y0[0], y0[1]);
            xa[g][ks][1] = pk2(y0[2], y0[3]);
            xa[g][ks][2] = pk2(y1[0], y1[1]);
            xa[g][ks][3] = pk2(y1[2], y1[3]);
        }
    }

#pragma unroll 1
    for (int i = 0; i < 12; ++i) {
        const int nt = nh * 12 + i;
        f32x4 acc0 = {0.f, 0.f, 0.f, 0.f};
        f32x4 acc1 = {0.f, 0.f, 0.f, 0.f};
#pragma unroll
        for (int ks = 0; ks < 3; ++ks) {
            s16x8 aw = *(const s16x8*)(w1 + (size_t)(nt * 16 + c16) * 96 + ks * 32 + g4 * 8);
            acc0 = __builtin_amdgcn_mfma_f32_16x16x32_bf16(aw, __builtin_bit_cast(s16x8, xa[0][ks]), acc0, 0, 0, 0);
            acc1 = __builtin_amdgcn_mfma_f32_16x16x32_bf16(aw, __builtin_bit_cast(s16x8, xa[1][ks]), acc1, 0, 0, 0);
        }
        const f32x4 bias = *(const f32x4*)(fc1_b + nt * 16 + g4 * 4);
#pragma unroll
        for (int g = 0; g < 2; ++g) {
            const f32x4 acc = (g == 0) ? acc0 : acc1;
            const int tok = mg * 32 + g * 16 + c16;
            float gv[4];
#pragma unroll
            for (int r = 0; r < 4; ++r) {
                const float v = acc[r] + bias[r];
                gv[r] = 0.5f * v * (1.0f + erff(v * 0.70710678118654752f));
            }
            const int chunk = (2 * nt + (g4 >> 1)) ^ (tok & 15);
            u32x2 pk = { pk2(gv[0], gv[1]), pk2(gv[2], gv[3]) };
            *(u32x2*)&sg[tok * 384 + chunk * 8 + (g4 & 1) * 4] = pk;
        }
    }
    __syncthreads();

    f32x4 facc[3][2];
    const int tokA = mg * 32 + c16;
    const int tokB = tokA + 16;
#pragma unroll 1
    for (int i = 0; i < 3; ++i) {
        const int nt = nh * 3 + i;
        f32x4 a0 = {0.f, 0.f, 0.f, 0.f};
        f32x4 a1 = {0.f, 0.f, 0.f, 0.f};
#pragma unroll
        for (int ks = 0; ks < 12; ++ks) {
            s16x8 aw = *(const s16x8*)(w2 + (size_t)(nt * 16 + c16) * 384 + ks * 32 + g4 * 8);
            s16x8 bg0 = *(const s16x8*)&sg[tokA * 384 + (((ks * 4 + g4) ^ (tokA & 15)) << 3)];
            s16x8 bg1 = *(const s16x8*)&sg[tokB * 384 + (((ks * 4 + g4) ^ (tokB & 15)) << 3)];
            a0 = __builtin_amdgcn_mfma_f32_16x16x32_bf16(aw, bg0, a0, 0, 0, 0);
            a1 = __builtin_amdgcn_mfma_f32_16x16x32_bf16(aw, bg1, a1, 0, 0, 0);
        }
        const f32x4 bias = *(const f32x4*)(fc2_b + nt * 16 + g4 * 4);
        const f32x4 resA = *(const f32x4*)(xl2 + (size_t)(t0 + tokA) * C_DIM + nt * 16 + g4 * 4);
        const f32x4 resB = *(const f32x4*)(xl2 + (size_t)(t0 + tokB) * C_DIM + nt * 16 + g4 * 4);
        facc[i][0] = a0 + bias + resA;
        facc[i][1] = a1 + bias + resB;
    }
    __syncthreads();

#pragma unroll
    for (int i = 0; i < 3; ++i) {
        const int nt = nh * 3 + i;
#pragma unroll
        for (int g = 0; g < 2; ++g) {
            const int tok = mg * 32 + g * 16 + c16;
#pragma unroll
            for (int r = 0; r < 4; ++r)
                s_res[tok * 97 + nt * 16 + g4 * 4 + r] = facc[i][g][r];
        }
    }
    __syncthreads();

    const int bb = t0 / SPATIAL;
    const int sbase = t0 % SPATIAL;
    for (int e = tid; e < 1536; e += 256) {
        const int c = e >> 4, tq = e & 15;
        f32x4 v;
        v[0] = s_res[(tq * 4 + 0) * 97 + c];
        v[1] = s_res[(tq * 4 + 1) * 97 + c];
        v[2] = s_res[(tq * 4 + 2) * 97 + c];
        v[3] = s_res[(tq * 4 + 3) * 97 + c];
        *(f32x4*)&out[((size_t)bb * C_DIM + c) * SPATIAL + sbase + tq * 4] = v;
    }
}

extern "C" void kernel_launch(void* const* d_in, const int* in_sizes, int n_in,
                              void* d_out, int out_size, void* d_ws, size_t ws_size,
                              hipStream_t stream) {
    const float* x      = (const float*)d_in[0];
    const float* g1     = (const float*)d_in[1];
    const float* be1    = (const float*)d_in[2];
    const float* g2     = (const float*)d_in[3];
    const float* be2    = (const float*)d_in[4];
    const float* qkv_w  = (const float*)d_in[5];
    const float* qkv_b  = (const float*)d_in[6];
    const float* proj_w = (const float*)d_in[7];
    const float* proj_b = (const float*)d_in[8];
    const float* rpb    = (const float*)d_in[9];
    const float* fc1_w  = (const float*)d_in[10];
    const float* fc1_b  = (const float*)d_in[11];
    const float* fc2_w  = (const float*)d_in[12];
    const float* fc2_b  = (const float*)d_in[13];
    float* out = (float*)d_out;

    float* xl  = (float*)d_ws;
    float* xl2 = xl + (size_t)NTOK * C_DIM;
    u16* wq = (u16*)(xl2 + (size_t)NTOK * C_DIM);
    u16* wp = wq + 27648;
    u16* w1 = wp + 9216;
    u16* w2 = w1 + 36864;
    float* rpbm = (float*)(w2 + 36864);

    k_prep<<<688, 256, 0, stream>>>(qkv_w, proj_w, fc1_w, fc2_w, rpb, wq, wp, w1, w2, rpbm);
    k_transpose_in<<<dim3(SPATIAL / 32, C_DIM / 32, BATCH), dim3(32, 8), 0, stream>>>(x, xl);
    k_win_attn<<<NWIN_TOT, 448, 0, stream>>>(xl, xl2, g1, be1, wq, qkv_b, wp, proj_b, rpbm);
    k_ffn<<<NTOK / 64, 256, 0, stream>>>(xl2, out, g2, be2, w1, fc1_b, w2, fc2_b);
}

// Round 18
// 358.938 us; speedup vs baseline: 1.1613x; 1.0674x over previous
//
#include <hip/hip_runtime.h>
#include <hip/hip_bf16.h>
#include <cmath>

#define C_DIM 96
#define RES_D 16
#define RES_H 56
#define RES_W 56
#define BATCH 4
#define SPATIAL (RES_D*RES_H*RES_W)      // 50176
#define NTOK (BATCH*SPATIAL)             // 200704
#define NWIN_TOT 2048
#define EPS_LN 1e-5f
#define QSCALE 0.2041241452319315f       // 1/sqrt(24)

#define MPAD 112        // window tokens padded 98 -> 112 (7 M-tiles, 7 waves)

// LDS layout (u16 element offsets) — full 4-head buffers + double P, 147.5KB, 1 block/CU
#define OFF_P   0              // [112][128]  P (heads 0,2); O overlay; proj input
#define OFF_Q   14336          // [4][112][32] q head-slabs
#define OFF_K   28672          // [4][112][32] k head-slabs
#define OFF_VT  43008          // [4][32][128] v^T head-slabs
#define OFF_P2  59392          // [112][128]  P (heads 1,3)
#define SM_TOT  73728          // 147456 B

typedef float f32x4 __attribute__((ext_vector_type(4)));
typedef short s16x8 __attribute__((ext_vector_type(8)));
typedef unsigned u32x4 __attribute__((ext_vector_type(4)));
typedef unsigned u32x2 __attribute__((ext_vector_type(2)));
typedef unsigned short u16;

__device__ __forceinline__ u16 f2bf(float f) {
    unsigned u = __float_as_uint(f);
    u = (u + 0x7FFF + ((u >> 16) & 1)) >> 16;
    return (u16)u;
}
// packed pair bf16 convert (RNE, same rounding as f2bf)
__device__ __forceinline__ unsigned pk2(float lo, float hi) {
    return (unsigned)f2bf(lo) | ((unsigned)f2bf(hi) << 16);
}
// chunk-swizzled addressing: [r][128] bf16, 16B chunks XOR'd by row
__device__ __forceinline__ int swzP(int r, int c) {
    return r * 128 + ((((c >> 3) ^ (r & 15)) << 3) | (c & 7));
}
// [r][32] bf16 buffers (q/k)
__device__ __forceinline__ int swzQ(int r, int c) {
    return r * 32 + ((((c >> 3) ^ ((r >> 1) & 3)) << 3) | (c & 7));
}

__device__ __forceinline__ float wave_reduce_sum(float v) {
#pragma unroll
    for (int off = 32; off > 0; off >>= 1) v += __shfl_xor(v, off, 64);
    return v;
}

// ---------------- prep: bf16-transpose weights + dense rpb matrix ----------------
// rpbm[h][128][128] indexed [q-row][k-col]: k-pad (m>=98) = -30000; q-pad row = 0.
__global__ __launch_bounds__(256) void k_prep(
    const float* __restrict__ qkv_w, const float* __restrict__ proj_w,
    const float* __restrict__ fc1_w, const float* __restrict__ fc2_w,
    const float* __restrict__ rpb_table,
    u16* __restrict__ wq, u16* __restrict__ wp, u16* __restrict__ w1,
    u16* __restrict__ w2, float* __restrict__ rpbm) {
    int i = blockIdx.x * 256 + threadIdx.x;
    if (i < 27648) {
        int j = i / 96, c = i % 96;
        wq[i] = f2bf(qkv_w[c * 288 + j]);
    } else if (i < 36864) {
        int t = i - 27648; int j = t / 96, c = t % 96;
        wp[t] = f2bf(proj_w[c * 96 + j]);
    } else if (i < 73728) {
        int t = i - 36864; int j = t / 96, c = t % 96;
        w1[t] = f2bf(fc1_w[c * 384 + j]);
    } else if (i < 110592) {
        int t = i - 73728; int c = t / 384, j = t % 384;
        w2[t] = f2bf(fc2_w[j * 96 + c]);
    } else if (i < 176128) {
        int t = i - 110592;
        int h = t / 16384, r = t % 16384, n = r / 128, m = r % 128;
        float v;
        if (m >= 98) {
            v = -30000.0f;                 // k-col pad: exp -> 0
        } else if (n >= 98) {
            v = 0.0f;                      // q-pad row: harmless finite scores
        } else {
            int dzn = n / 49, rn = n % 49, hyn = rn / 7, wxn = rn % 7;
            int dzm = m / 49, rm = m % 49, hym = rm / 7, wxm = rm % 7;
            int ridx = (dzn - dzm + 1) * 169 + (hyn - hym + 6) * 13 + (wxn - wxm + 6);
            v = rpb_table[ridx * 4 + h];
        }
        rpbm[t] = v;
    }
}

// ---------------- (B,C,S) -> (B,S,C) transpose ----------------
__global__ __launch_bounds__(256) void k_transpose_in(const float* __restrict__ x,
                                                      float* __restrict__ xl) {
    __shared__ float tile[32][33];
    const int b = blockIdx.z;
    const int s0 = blockIdx.x * 32;
    const int c0 = blockIdx.y * 32;
    const float* xb = x + (size_t)b * C_DIM * SPATIAL;
    float* xlb = xl + (size_t)b * SPATIAL * C_DIM;
    const int ts = threadIdx.x, tc = threadIdx.y;
#pragma unroll
    for (int i = 0; i < 32; i += 8)
        tile[tc + i][ts] = xb[(size_t)(c0 + tc + i) * SPATIAL + s0 + ts];
    __syncthreads();
#pragma unroll
    for (int i = 0; i < 32; i += 8)
        xlb[(size_t)(s0 + tc + i) * C_DIM + c0 + ts] = tile[ts][tc + i];
}

// ---------------- per-window attention: token-major, 4-head barrier-free, double-P ----------------
__global__ __launch_bounds__(448, 2) void k_win_attn(
    const float* __restrict__ xl, float* __restrict__ xl2,
    const float* __restrict__ g1, const float* __restrict__ b1,
    const u16* __restrict__ wqkv, const float* __restrict__ qkv_b,
    const u16* __restrict__ wproj, const float* __restrict__ proj_b,
    const float* __restrict__ rpbm) {
    __shared__ __align__(16) u16 sm[SM_TOT];
    __shared__ __align__(16) int s_gtok[MPAD];
    __shared__ __align__(16) int s_reg[MPAD];

    const int tid = threadIdx.x;
    const int lane = tid & 63;
    const int wv = tid >> 6;            // 0..6, owns M-tile wv
    const int g4 = lane >> 4;
    const int c16 = lane & 15;
    const int mt = wv;

    const int wid = blockIdx.x;
    const int b = wid >> 9;
    const int rem = wid & 511;
    const int wdi = rem >> 6, whi = (rem >> 3) & 7, wwi = rem & 7;

    // ---- targeted zeroing (pads only) ----
    for (int i = tid; i < 7168; i += 448) {            // q/k pad cols 24..31, 4 slabs each
        int c = 24 + (i & 7);
        int hb = (i >> 3) / 112;                        // 0..7
        int r = (i >> 3) % 112;
        int base = (hb < 4) ? (OFF_Q + hb * 3584) : (OFF_K + (hb - 4) * 3584);
        sm[base + swzQ(r, c)] = 0;
    }
    for (int i = tid; i < 4096; i += 448) {            // vt pad d-rows 24..31 (all cols)
        int h = i >> 10, rr = 24 + ((i >> 7) & 7), c = i & 127;
        sm[OFF_VT + h * 4096 + swzP(rr, c)] = 0;
    }
    for (int i = tid; i < 1536; i += 448) {            // vt tok-cols 112..127, d-rows 0..23
        int h = i / 384, r = (i % 384) >> 4, c = 112 + (i & 15);
        sm[OFF_VT + h * 4096 + swzP(r, c)] = 0;
    }
    for (int i = tid; i < 3584; i += 448) {            // P0+P1 cols 112..127 (fixed modulo)
        int pb = (i >= 1792) ? OFF_P2 : OFF_P;
        int t = (i >= 1792) ? (i - 1792) : i;
        int r = t >> 4, c = 112 + (t & 15);
        sm[pb + swzP(r, c)] = 0;
    }
    if (tid < MPAD) {
        if (tid < 98) {
            const int n = tid;
            const int dz = n / 49, r = n % 49, hy = r / 7, wx = r % 7;
            const int rd = wdi * 2 + dz, rh = whi * 7 + hy, rw = wwi * 7 + wx;
            int od = rd + 1; if (od >= RES_D) od -= RES_D;
            int oh = rh + 3; if (oh >= RES_H) oh -= RES_H;
            int ow = rw + 3; if (ow >= RES_W) ow -= RES_W;
            s_gtok[n] = ((b * RES_D + od) * RES_H + oh) * RES_W + ow;
            const int gd = (rd < 14) ? 0 : (rd < 15 ? 1 : 2);
            const int gh = (rh < 49) ? 0 : (rh < 53 ? 1 : 2);
            const int gw = (rw < 49) ? 0 : (rw < 53 ? 1 : 2);
            s_reg[n] = gd * 9 + gh * 3 + gw;
        } else { s_gtok[tid] = 0; s_reg[tid] = -1; }
    }
    __syncthreads();                                   // barrier 1 (gtok + pad zeros)

    const int mytok = mt * 16 + c16;                   // this lane's token row
    const float live = (mytok < 98) ? 1.0f : 0.0f;

    // ---- LN1 -> registers, fragment layout (row = mytok, cols ks*32+g4*8) ----
    u32x4 xa[3];
    {
        const float* src = xl + (size_t)s_gtok[mytok] * C_DIM;
        f32x4 xv0 = *(const f32x4*)(src + 0 * 32 + g4 * 8);
        f32x4 xv1 = *(const f32x4*)(src + 0 * 32 + g4 * 8 + 4);
        f32x4 xv2 = *(const f32x4*)(src + 1 * 32 + g4 * 8);
        f32x4 xv3 = *(const f32x4*)(src + 1 * 32 + g4 * 8 + 4);
        f32x4 xv4 = *(const f32x4*)(src + 2 * 32 + g4 * 8);
        f32x4 xv5 = *(const f32x4*)(src + 2 * 32 + g4 * 8 + 4);
        float lsum = (xv0[0]+xv0[1]+xv0[2]+xv0[3]) + (xv1[0]+xv1[1]+xv1[2]+xv1[3])
                   + (xv2[0]+xv2[1]+xv2[2]+xv2[3]) + (xv3[0]+xv3[1]+xv3[2]+xv3[3])
                   + (xv4[0]+xv4[1]+xv4[2]+xv4[3]) + (xv5[0]+xv5[1]+xv5[2]+xv5[3]);
        lsum += __shfl_xor(lsum, 16, 64);
        lsum += __shfl_xor(lsum, 32, 64);
        const float mu = lsum * (1.0f / 96.0f);
        f32x4 d0 = xv0 - mu, d1 = xv1 - mu, d2 = xv2 - mu,
              d3 = xv3 - mu, d4 = xv4 - mu, d5 = xv5 - mu;
        float lvv = (d0[0]*d0[0]+d0[1]*d0[1]+d0[2]*d0[2]+d0[3]*d0[3])
                  + (d1[0]*d1[0]+d1[1]*d1[1]+d1[2]*d1[2]+d1[3]*d1[3])
                  + (d2[0]*d2[0]+d2[1]*d2[1]+d2[2]*d2[2]+d2[3]*d2[3])
                  + (d3[0]*d3[0]+d3[1]*d3[1]+d3[2]*d3[2]+d3[3]*d3[3])
                  + (d4[0]*d4[0]+d4[1]*d4[1]+d4[2]*d4[2]+d4[3]*d4[3])
                  + (d5[0]*d5[0]+d5[1]*d5[1]+d5[2]*d5[2]+d5[3]*d5[3]);
        lvv += __shfl_xor(lvv, 16, 64);
        lvv += __shfl_xor(lvv, 32, 64);
        const float rstd = rsqrtf(lvv * (1.0f / 96.0f) + EPS_LN) * live;
#pragma unroll
        for (int ks = 0; ks < 3; ++ks) {
            const f32x4 ea = (ks == 0) ? d0 : (ks == 1) ? d2 : d4;
            const f32x4 eb = (ks == 0) ? d1 : (ks == 1) ? d3 : d5;
            f32x4 ga = *(const f32x4*)(g1 + ks * 32 + g4 * 8);
            f32x4 gb = *(const f32x4*)(g1 + ks * 32 + g4 * 8 + 4);
            f32x4 ba = *(const f32x4*)(b1 + ks * 32 + g4 * 8);
            f32x4 bb = *(const f32x4*)(b1 + ks * 32 + g4 * 8 + 4);
            f32x4 y0 = ea * rstd * ga + ba * live;
            f32x4 y1 = eb * rstd * gb + bb * live;
            xa[ks][0] = pk2(y0[0], y0[1]);
            xa[ks][1] = pk2(y0[2], y0[3]);
            xa[ks][2] = pk2(y1[0], y1[1]);
            xa[ks][3] = pk2(y1[2], y1[3]);
        }
    }

    // ---- QKV: q,k swapped (vector stores); v original (vector token-run stores) ----
#pragma unroll
    for (int sel = 0; sel < 3; ++sel) {
#pragma unroll
        for (int t = 0; t < 6; ++t) {
            const int nt = sel * 6 + t;
            f32x4 acc = {0.f, 0.f, 0.f, 0.f};
            if (sel < 2) {
#pragma unroll
                for (int ks = 0; ks < 3; ++ks) {
                    s16x8 bw = *(const s16x8*)(wqkv + (size_t)(nt * 16 + c16) * 96 + ks * 32 + g4 * 8);
                    acc = __builtin_amdgcn_mfma_f32_16x16x32_bf16(bw, __builtin_bit_cast(s16x8, xa[ks]), acc, 0, 0, 0);
                }
                const int jb = t * 16 + g4 * 4;        // 0..92, 4-run never straddles a head
                const f32x4 b4 = *(const f32x4*)(qkv_b + sel * 96 + jb);
                f32x4 v = acc + b4;
                if (sel == 0) { v[0] *= QSCALE; v[1] *= QSCALE; v[2] *= QSCALE; v[3] *= QSCALE; }
                const int h = jb / 24, db = jb - h * 24;
                u32x2 pkv = { pk2(v[0], v[1]), pk2(v[2], v[3]) };
                const int base = (sel == 0 ? OFF_Q : OFF_K) + h * 3584;
                *(u32x2*)&sm[base + swzQ(mytok, db)] = pkv;
            } else {
#pragma unroll
                for (int ks = 0; ks < 3; ++ks) {
                    s16x8 bw = *(const s16x8*)(wqkv + (size_t)(nt * 16 + c16) * 96 + ks * 32 + g4 * 8);
                    acc = __builtin_amdgcn_mfma_f32_16x16x32_bf16(__builtin_bit_cast(s16x8, xa[ks]), bw, acc, 0, 0, 0);
                }
                const int j96 = t * 16 + c16;
                const float bias = qkv_b[192 + j96];
                const int h = j96 / 24, d = j96 - h * 24;
                const int row0 = mt * 16 + g4 * 4;
                f32x4 v = acc + bias;
                u32x2 pkv = { pk2(v[0], v[1]), pk2(v[2], v[3]) };
                *(u32x2*)&sm[OFF_VT + h * 4096 + swzP(d, row0)] = pkv;
            }
        }
    }
    __syncthreads();                                   // barrier 2 (q/k/vt complete)

    // ---- shift-mask bits for this lane's 28 k-entries (bit nt*4+r) ----
    const int rgq = s_reg[mytok];
    unsigned mbits = 0;
#pragma unroll
    for (int nt = 0; nt < 7; ++nt) {
        const int4 cr = *(const int4*)&s_reg[nt * 16 + g4 * 4];
        mbits |= (unsigned)(cr.x != rgq) << (nt * 4 + 0);
        mbits |= (unsigned)(cr.y != rgq) << (nt * 4 + 1);
        mbits |= (unsigned)(cr.z != rgq) << (nt * 4 + 2);
        mbits |= (unsigned)(cr.w != rgq) << (nt * 4 + 3);
    }

    // ---- 4 heads, barrier-free, token-major; alternate P buffers for cross-head ILP ----
    unsigned ogp[4][2][2];
#pragma unroll
    for (int h = 0; h < 4; ++h) {
        const int pbase = (h & 1) ? OFF_P2 : OFF_P;
        const s16x8 aq = *(const s16x8*)&sm[OFF_Q + h * 3584 + swzQ(mytok, g4 * 8)];
        const float* rq = rpbm + h * 16384 + mytok * 128;
        float smr = 0.f;
#pragma unroll
        for (int nt = 0; nt < 7; ++nt) {
            s16x8 ak = *(const s16x8*)&sm[OFF_K + h * 3584 + swzQ(nt * 16 + c16, g4 * 8)];
            f32x4 z = {0.f, 0.f, 0.f, 0.f};
            f32x4 sc = __builtin_amdgcn_mfma_f32_16x16x32_bf16(ak, aq, z, 0, 0, 0);  // swapped: row=k, col=q
            const f32x4 rv = *(const f32x4*)&rq[nt * 16 + g4 * 4];
            float s0 = sc[0] + rv[0] - 100.0f * (float)((mbits >> (nt * 4 + 0)) & 1u);
            float s1 = sc[1] + rv[1] - 100.0f * (float)((mbits >> (nt * 4 + 1)) & 1u);
            float s2 = sc[2] + rv[2] - 100.0f * (float)((mbits >> (nt * 4 + 2)) & 1u);
            float s3 = sc[3] + rv[3] - 100.0f * (float)((mbits >> (nt * 4 + 3)) & 1u);
            const float e0 = __expf(s0), e1 = __expf(s1), e2 = __expf(s2), e3 = __expf(s3);
            smr += (e0 + e1) + (e2 + e3);
            u32x2 pkv = { pk2(e0, e1), pk2(e2, e3) };
            *(u32x2*)&sm[pbase + swzP(mytok, nt * 16 + g4 * 4)] = pkv;
        }
        smr += __shfl_xor(smr, 16, 64);
        smr += __shfl_xor(smr, 32, 64);
        const float iq = 1.0f / fmaxf(smr, 1e-30f);
        // PV swapped: A=VT (rows=d), B=P (cols=q tokens) -> lane holds 4 d of own token
#pragma unroll
        for (int dt = 0; dt < 2; ++dt) {
            f32x4 acc = {0.f, 0.f, 0.f, 0.f};
#pragma unroll
            for (int ks = 0; ks < 4; ++ks) {
                s16x8 av = *(const s16x8*)&sm[OFF_VT + h * 4096 + swzP(dt * 16 + c16, ks * 32 + g4 * 8)];
                s16x8 bp = *(const s16x8*)&sm[pbase + swzP(mt * 16 + c16, ks * 32 + g4 * 8)];
                acc = __builtin_amdgcn_mfma_f32_16x16x32_bf16(av, bp, acc, 0, 0, 0);
            }
            ogp[h][dt][0] = pk2(acc[0] * iq, acc[1] * iq);
            ogp[h][dt][1] = pk2(acc[2] * iq, acc[3] * iq);
        }
    }

    // ---- O -> P0 region (own token row, cols 0..95), vector stores ----
#pragma unroll
    for (int h = 0; h < 4; ++h) {
#pragma unroll
        for (int dt = 0; dt < 2; ++dt) {
            const int db = dt * 16 + g4 * 4;
            if (db < 24) {
                u32x2 v = { ogp[h][dt][0], ogp[h][dt][1] };
                *(u32x2*)&sm[OFF_P + swzP(mytok, h * 24 + db)] = v;
            }
        }
    }

    // ---- proj (swapped) + residual -> xl2, vector f32x4 I/O ----
    const int gq = s_gtok[mytok];
#pragma unroll
    for (int nt = 0; nt < 6; ++nt) {
        f32x4 acc = {0.f, 0.f, 0.f, 0.f};
#pragma unroll
        for (int ks = 0; ks < 3; ++ks) {
            s16x8 aw = *(const s16x8*)(wproj + (size_t)(nt * 16 + c16) * 96 + ks * 32 + g4 * 8);
            s16x8 bo = *(const s16x8*)&sm[OFF_P + swzP(mt * 16 + c16, ks * 32 + g4 * 8)];
            acc = __builtin_amdgcn_mfma_f32_16x16x32_bf16(aw, bo, acc, 0, 0, 0);
        }
        if (mytok < 98) {
            const int cb = nt * 16 + g4 * 4;
            const f32x4 pb4 = *(const f32x4*)(proj_b + cb);
            const f32x4 res = *(const f32x4*)(xl + (size_t)gq * C_DIM + cb);
            *(f32x4*)(xl2 + (size_t)gq * C_DIM + cb) = acc + pb4 + res;
        }
    }
}

// ---------------- FFN v3 (unchanged from round 12/14, measured good) ----------------
__global__ __launch_bounds__(256, 3) void k_ffn(
    const float* __restrict__ xl2, float* __restrict__ out,
    const float* __restrict__ g2, const float* __restrict__ b2,
    const u16* __restrict__ w1, const float* __restrict__ fc1_b,
    const u16* __restrict__ w2, const float* __restrict__ fc2_b) {
    __shared__ __align__(16) u16 sg[64 * 384];   // 49152 B
    float* s_res = (float*)sg;                   // [64][97] f32, aliases sg

    const int tid = threadIdx.x;
    const int lane = tid & 63;
    const int wave = tid >> 6;
    const int g4 = lane >> 4, c16 = lane & 15;
    const int mg = wave & 1;
    const int nh = wave >> 1;
    const int t0 = blockIdx.x * 64;

    u32x4 xa[2][3];
#pragma unroll
    for (int g = 0; g < 2; ++g) {
        const int tok = mg * 32 + g * 16 + c16;
        const float* src = xl2 + (size_t)(t0 + tok) * C_DIM;
        f32x4 xv0 = *(const f32x4*)(src + 0 * 32 + g4 * 8);
        f32x4 xv1 = *(const f32x4*)(src + 0 * 32 + g4 * 8 + 4);
        f32x4 xv2 = *(const f32x4*)(src + 1 * 32 + g4 * 8);
        f32x4 xv3 = *(const f32x4*)(src + 1 * 32 + g4 * 8 + 4);
        f32x4 xv4 = *(const f32x4*)(src + 2 * 32 + g4 * 8);
        f32x4 xv5 = *(const f32x4*)(src + 2 * 32 + g4 * 8 + 4);
        float lsum = (xv0[0]+xv0[1]+xv0[2]+xv0[3]) + (xv1[0]+xv1[1]+xv1[2]+xv1[3])
                   + (xv2[0]+xv2[1]+xv2[2]+xv2[3]) + (xv3[0]+xv3[1]+xv3[2]+xv3[3])
                   + (xv4[0]+xv4[1]+xv4[2]+xv4[3]) + (xv5[0]+xv5[1]+xv5[2]+xv5[3]);
        lsum += __shfl_xor(lsum, 16, 64);
        lsum += __shfl_xor(lsum, 32, 64);
        const float mu = lsum * (1.0f / 96.0f);
        f32x4 d0 = xv0 - mu, d1 = xv1 - mu, d2 = xv2 - mu,
              d3 = xv3 - mu, d4 = xv4 - mu, d5 = xv5 - mu;
        float lvv = (d0[0]*d0[0]+d0[1]*d0[1]+d0[2]*d0[2]+d0[3]*d0[3])
                  + (d1[0]*d1[0]+d1[1]*d1[1]+d1[2]*d1[2]+d1[3]*d1[3])
                  + (d2[0]*d2[0]+d2[1]*d2[1]+d2[2]*d2[2]+d2[3]*d2[3])
                  + (d3[0]*d3[0]+d3[1]*d3[1]+d3[2]*d3[2]+d3[3]*d3[3])
                  + (d4[0]*d4[0]+d4[1]*d4[1]+d4[2]*d4[2]+d4[3]*d4[3])
                  + (d5[0]*d5[0]+d5[1]*d5[1]+d5[2]*d5[2]+d5[3]*d5[3]);
        lvv += __shfl_xor(lvv, 16, 64);
        lvv += __shfl_xor(lvv, 32, 64);
        const float rstd = rsqrtf(lvv * (1.0f / 96.0f) + EPS_LN);
#pragma unroll
        for (int ks = 0; ks < 3; ++ks) {
            const f32x4 ea = (ks == 0) ? d0 : (ks == 1) ? d2 : d4;
            const f32x4 eb = (ks == 0) ? d1 : (ks == 1) ? d3 : d5;
            f32x4 ga = *(const f32x4*)(g2 + ks * 32 + g4 * 8);
            f32x4 gb = *(const f32x4*)(g2 + ks * 32 + g4 * 8 + 4);
            f32x4 ba = *(const f32x4*)(b2 + ks * 32 + g4 * 8);
            f32x4 bb = *(const f32x4*)(b2 + ks * 32 + g4 * 8 + 4);
            f32x4 y0 = ea * rstd * ga + ba;
            f32x4 y1 = eb * rstd * gb + bb;
            xa[g][ks][0] = pk2(y0[0], y0[1]);
            xa[g][ks][1] = pk2(y0[2], y0[3]);
            xa[g][ks][2] = pk2(y1[0], y1[1]);
            xa[g][ks][3] = pk2(y1[2], y1[3]);
        }
    }

#pragma unroll 1
    for (int i = 0; i < 12; ++i) {
        const int nt = nh * 12 + i;
        f32x4 acc0 = {0.f, 0.f, 0.f, 0.f};
        f32x4 acc1 = {0.f, 0.f, 0.f, 0.f};
#pragma unroll
        for (int ks = 0; ks < 3; ++ks) {
            s16x8 aw = *(const s16x8*)(w1 + (size_t)(nt * 16 + c16) * 96 + ks * 32 + g4 * 8);
            acc0 = __builtin_amdgcn_mfma_f32_16x16x32_bf16(aw, __builtin_bit_cast(s16x8, xa[0][ks]), acc0, 0, 0, 0);
            acc1 = __builtin_amdgcn_mfma_f32_16x16x32_bf16(aw, __builtin_bit_cast(s16x8, xa[1][ks]), acc1, 0, 0, 0);
        }
        const f32x4 bias = *(const f32x4*)(fc1_b + nt * 16 + g4 * 4);
#pragma unroll
        for (int g = 0; g < 2; ++g) {
            const f32x4 acc = (g == 0) ? acc0 : acc1;
            const int tok = mg * 32 + g * 16 + c16;
            float gv[4];
#pragma unroll
            for (int r = 0; r < 4; ++r) {
                const float v = acc[r] + bias[r];
                gv[r] = 0.5f * v * (1.0f + erff(v * 0.70710678118654752f));
            }
            const int chunk = (2 * nt + (g4 >> 1)) ^ (tok & 15);
            u32x2 pk = { pk2(gv[0], gv[1]), pk2(gv[2], gv[3]) };
            *(u32x2*)&sg[tok * 384 + chunk * 8 + (g4 & 1) * 4] = pk;
        }
    }
    __syncthreads();

    f32x4 facc[3][2];
    const int tokA = mg * 32 + c16;
    const int tokB = tokA + 16;
#pragma unroll 1
    for (int i = 0; i < 3; ++i) {
        const int nt = nh * 3 + i;
        f32x4 a0 = {0.f, 0.f, 0.f, 0.f};
        f32x4 a1 = {0.f, 0.f, 0.f, 0.f};
#pragma unroll
        for (int ks = 0; ks < 12; ++ks) {
            s16x8 aw = *(const s16x8*)(w2 + (size_t)(nt * 16 + c16) * 384 + ks * 32 + g4 * 8);
            s16x8 bg0 = *(const s16x8*)&sg[tokA * 384 + (((ks * 4 + g4) ^ (tokA & 15)) << 3)];
            s16x8 bg1 = *(const s16x8*)&sg[tokB * 384 + (((ks * 4 + g4) ^ (tokB & 15)) << 3)];
            a0 = __builtin_amdgcn_mfma_f32_16x16x32_bf16(aw, bg0, a0, 0, 0, 0);
            a1 = __builtin_amdgcn_mfma_f32_16x16x32_bf16(aw, bg1, a1, 0, 0, 0);
        }
        const f32x4 bias = *(const f32x4*)(fc2_b + nt * 16 + g4 * 4);
        const f32x4 resA = *(const f32x4*)(xl2 + (size_t)(t0 + tokA) * C_DIM + nt * 16 + g4 * 4);
        const f32x4 resB = *(const f32x4*)(xl2 + (size_t)(t0 + tokB) * C_DIM + nt * 16 + g4 * 4);
        facc[i][0] = a0 + bias + resA;
        facc[i][1] = a1 + bias + resB;
    }
    __syncthreads();

#pragma unroll
    for (int i = 0; i < 3; ++i) {
        const int nt = nh * 3 + i;
#pragma unroll
        for (int g = 0; g < 2; ++g) {
            const int tok = mg * 32 + g * 16 + c16;
#pragma unroll
            for (int r = 0; r < 4; ++r)
                s_res[tok * 97 + nt * 16 + g4 * 4 + r] = facc[i][g][r];
        }
    }
    __syncthreads();

    const int bb = t0 / SPATIAL;
    const int sbase = t0 % SPATIAL;
    for (int e = tid; e < 1536; e += 256) {
        const int c = e >> 4, tq = e & 15;
        f32x4 v;
        v[0] = s_res[(tq * 4 + 0) * 97 + c];
        v[1] = s_res[(tq * 4 + 1) * 97 + c];
        v[2] = s_res[(tq * 4 + 2) * 97 + c];
        v[3] = s_res[(tq * 4 + 3) * 97 + c];
        *(f32x4*)&out[((size_t)bb * C_DIM + c) * SPATIAL + sbase + tq * 4] = v;
    }
}

extern "C" void kernel_launch(void* const* d_in, const int* in_sizes, int n_in,
                              void* d_out, int out_size, void* d_ws, size_t ws_size,
                              hipStream_t stream) {
    const float* x      = (const float*)d_in[0];
    const float* g1     = (const float*)d_in[1];
    const float* be1    = (const float*)d_in[2];
    const float* g2     = (const float*)d_in[3];
    const float* be2    = (const float*)d_in[4];
    const float* qkv_w  = (const float*)d_in[5];
    const float* qkv_b  = (const float*)d_in[6];
    const float* proj_w = (const float*)d_in[7];
    const float* proj_b = (const float*)d_in[8];
    const float* rpb    = (const float*)d_in[9];
    const float* fc1_w  = (const float*)d_in[10];
    const float* fc1_b  = (const float*)d_in[11];
    const float* fc2_w  = (const float*)d_in[12];
    const float* fc2_b  = (const float*)d_in[13];
    float* out = (float*)d_out;

    float* xl  = (float*)d_ws;
    float* xl2 = xl + (size_t)NTOK * C_DIM;
    u16* wq = (u16*)(xl2 + (size_t)NTOK * C_DIM);
    u16* wp = wq + 27648;
    u16* w1 = wp + 9216;
    u16* w2 = w1 + 36864;
    float* rpbm = (float*)(w2 + 36864);

    k_prep<<<688, 256, 0, stream>>>(qkv_w, proj_w, fc1_w, fc2_w, rpb, wq, wp, w1, w2, rpbm);
    k_transpose_in<<<dim3(SPATIAL / 32, C_DIM / 32, BATCH), dim3(32, 8), 0, stream>>>(x, xl);
    k_win_attn<<<NWIN_TOT, 448, 0, stream>>>(xl, xl2, g1, be1, wq, qkv_b, wp, proj_b, rpbm);
    k_ffn<<<NTOK / 64, 256, 0, stream>>>(xl2, out, g2, be2, w1, fc1_b, w2, fc2_b);
}

// Round 19
// 354.393 us; speedup vs baseline: 1.1762x; 1.0128x over previous
//
#include <hip/hip_runtime.h>
#include <hip/hip_bf16.h>
#include <cmath>

#define C_DIM 96
#define RES_D 16
#define RES_H 56
#define RES_W 56
#define BATCH 4
#define SPATIAL (RES_D*RES_H*RES_W)      // 50176
#define NTOK (BATCH*SPATIAL)             // 200704
#define NWIN_TOT 2048
#define EPS_LN 1e-5f
#define QSCALE 0.2041241452319315f       // 1/sqrt(24)

#define MPAD 112        // window tokens padded 98 -> 112 (7 M-tiles, 7 waves)

// LDS layout (u16 element offsets) — full 4-head buffers, 1 block/CU by design
#define OFF_P   0              // [112][128]  P; later O overlay (own rows)
#define OFF_Q   14336          // [4][112][32] q head-slabs
#define OFF_K   28672          // [4][112][32] k head-slabs
#define OFF_VT  43008          // [4][32][128] v^T head-slabs
#define SM_TOT  59392          // 118784 B

typedef float f32x4 __attribute__((ext_vector_type(4)));
typedef short s16x8 __attribute__((ext_vector_type(8)));
typedef unsigned u32x4 __attribute__((ext_vector_type(4)));
typedef unsigned u32x2 __attribute__((ext_vector_type(2)));
typedef unsigned short u16;

__device__ __forceinline__ u16 f2bf(float f) {
    unsigned u = __float_as_uint(f);
    u = (u + 0x7FFF + ((u >> 16) & 1)) >> 16;
    return (u16)u;
}
// packed pair bf16 convert (RNE, same rounding as f2bf)
__device__ __forceinline__ unsigned pk2(float lo, float hi) {
    return (unsigned)f2bf(lo) | ((unsigned)f2bf(hi) << 16);
}
// chunk-swizzled addressing: [r][128] bf16, 16B chunks XOR'd by row
__device__ __forceinline__ int swzP(int r, int c) {
    return r * 128 + ((((c >> 3) ^ (r & 15)) << 3) | (c & 7));
}
// [r][32] bf16 buffers (q/k)
__device__ __forceinline__ int swzQ(int r, int c) {
    return r * 32 + ((((c >> 3) ^ ((r >> 1) & 3)) << 3) | (c & 7));
}

__device__ __forceinline__ float wave_reduce_sum(float v) {
#pragma unroll
    for (int off = 32; off > 0; off >>= 1) v += __shfl_xor(v, off, 64);
    return v;
}

// ---------------- prep: bf16-transpose weights + dense rpb matrix ----------------
// rpbm[h][128][128] indexed [q-row][k-col]: k-pad (m>=98) = -30000; q-pad row = 0.
__global__ __launch_bounds__(256) void k_prep(
    const float* __restrict__ qkv_w, const float* __restrict__ proj_w,
    const float* __restrict__ fc1_w, const float* __restrict__ fc2_w,
    const float* __restrict__ rpb_table,
    u16* __restrict__ wq, u16* __restrict__ wp, u16* __restrict__ w1,
    u16* __restrict__ w2, float* __restrict__ rpbm) {
    int i = blockIdx.x * 256 + threadIdx.x;
    if (i < 27648) {
        int j = i / 96, c = i % 96;
        wq[i] = f2bf(qkv_w[c * 288 + j]);
    } else if (i < 36864) {
        int t = i - 27648; int j = t / 96, c = t % 96;
        wp[t] = f2bf(proj_w[c * 96 + j]);
    } else if (i < 73728) {
        int t = i - 36864; int j = t / 96, c = t % 96;
        w1[t] = f2bf(fc1_w[c * 384 + j]);
    } else if (i < 110592) {
        int t = i - 73728; int c = t / 384, j = t % 384;
        w2[t] = f2bf(fc2_w[j * 96 + c]);
    } else if (i < 176128) {
        int t = i - 110592;
        int h = t / 16384, r = t % 16384, n = r / 128, m = r % 128;
        float v;
        if (m >= 98) {
            v = -30000.0f;                 // k-col pad: exp -> 0
        } else if (n >= 98) {
            v = 0.0f;                      // q-pad row: harmless finite scores
        } else {
            int dzn = n / 49, rn = n % 49, hyn = rn / 7, wxn = rn % 7;
            int dzm = m / 49, rm = m % 49, hym = rm / 7, wxm = rm % 7;
            int ridx = (dzn - dzm + 1) * 169 + (hyn - hym + 6) * 13 + (wxn - wxm + 6);
            v = rpb_table[ridx * 4 + h];
        }
        rpbm[t] = v;
    }
}

// ---------------- (B,C,S) -> (B,S,C) transpose ----------------
__global__ __launch_bounds__(256) void k_transpose_in(const float* __restrict__ x,
                                                      float* __restrict__ xl) {
    __shared__ float tile[32][33];
    const int b = blockIdx.z;
    const int s0 = blockIdx.x * 32;
    const int c0 = blockIdx.y * 32;
    const float* xb = x + (size_t)b * C_DIM * SPATIAL;
    float* xlb = xl + (size_t)b * SPATIAL * C_DIM;
    const int ts = threadIdx.x, tc = threadIdx.y;
#pragma unroll
    for (int i = 0; i < 32; i += 8)
        tile[tc + i][ts] = xb[(size_t)(c0 + tc + i) * SPATIAL + s0 + ts];
    __syncthreads();
#pragma unroll
    for (int i = 0; i < 32; i += 8)
        xlb[(size_t)(s0 + tc + i) * C_DIM + c0 + ts] = tile[ts][tc + i];
}

// ---------------- per-window attention: token-major (swapped-operand) form ----------------
__global__ __launch_bounds__(448, 2) void k_win_attn(
    const float* __restrict__ xl, float* __restrict__ xl2,
    const float* __restrict__ g1, const float* __restrict__ b1,
    const u16* __restrict__ wqkv, const float* __restrict__ qkv_b,
    const u16* __restrict__ wproj, const float* __restrict__ proj_b,
    const float* __restrict__ rpbm) {
    __shared__ __align__(16) u16 sm[SM_TOT];
    __shared__ __align__(16) int s_gtok[MPAD];
    __shared__ __align__(16) int s_reg[MPAD];

    const int tid = threadIdx.x;
    const int lane = tid & 63;
    const int wv = tid >> 6;            // 0..6, owns M-tile wv
    const int g4 = lane >> 4;
    const int c16 = lane & 15;
    const int mt = wv;

    const int wid = blockIdx.x;
    const int b = wid >> 9;
    const int rem = wid & 511;
    const int wdi = rem >> 6, whi = (rem >> 3) & 7, wwi = rem & 7;

    // ---- targeted zeroing (pads only) ----
    for (int i = tid; i < 7168; i += 448) {            // q/k pad cols 24..31, 4 slabs each
        int c = 24 + (i & 7);
        int hb = (i >> 3) / 112;                        // 0..7
        int r = (i >> 3) % 112;
        int base = (hb < 4) ? (OFF_Q + hb * 3584) : (OFF_K + (hb - 4) * 3584);
        sm[base + swzQ(r, c)] = 0;
    }
    for (int i = tid; i < 4096; i += 448) {            // vt pad d-rows 24..31 (all cols)
        int h = i >> 10, rr = 24 + ((i >> 7) & 7), c = i & 127;
        sm[OFF_VT + h * 4096 + swzP(rr, c)] = 0;
    }
    for (int i = tid; i < 1536; i += 448) {            // vt tok-cols 112..127, d-rows 0..23
        int h = i / 384, r = (i % 384) >> 4, c = 112 + (i & 15);
        sm[OFF_VT + h * 4096 + swzP(r, c)] = 0;
    }
    for (int i = tid; i < 1792; i += 448) {            // P cols 112..127
        int r = i >> 4, c = 112 + (i & 15);
        sm[OFF_P + swzP(r, c)] = 0;
    }
    if (tid < MPAD) {
        if (tid < 98) {
            const int n = tid;
            const int dz = n / 49, r = n % 49, hy = r / 7, wx = r % 7;
            const int rd = wdi * 2 + dz, rh = whi * 7 + hy, rw = wwi * 7 + wx;
            int od = rd + 1; if (od >= RES_D) od -= RES_D;
            int oh = rh + 3; if (oh >= RES_H) oh -= RES_H;
            int ow = rw + 3; if (ow >= RES_W) ow -= RES_W;
            s_gtok[n] = ((b * RES_D + od) * RES_H + oh) * RES_W + ow;
            const int gd = (rd < 14) ? 0 : (rd < 15 ? 1 : 2);
            const int gh = (rh < 49) ? 0 : (rh < 53 ? 1 : 2);
            const int gw = (rw < 49) ? 0 : (rw < 53 ? 1 : 2);
            s_reg[n] = gd * 9 + gh * 3 + gw;
        } else { s_gtok[tid] = 0; s_reg[tid] = -1; }
    }
    __syncthreads();                                   // barrier 1 (gtok + pad zeros)

    const int mytok = mt * 16 + c16;                   // this lane's token row
    const float live = (mytok < 98) ? 1.0f : 0.0f;

    // ---- LN1 -> registers, fragment layout (row = mytok, cols ks*32+g4*8) ----
    u32x4 xa[3];
    {
        const float* src = xl + (size_t)s_gtok[mytok] * C_DIM;
        f32x4 xv0 = *(const f32x4*)(src + 0 * 32 + g4 * 8);
        f32x4 xv1 = *(const f32x4*)(src + 0 * 32 + g4 * 8 + 4);
        f32x4 xv2 = *(const f32x4*)(src + 1 * 32 + g4 * 8);
        f32x4 xv3 = *(const f32x4*)(src + 1 * 32 + g4 * 8 + 4);
        f32x4 xv4 = *(const f32x4*)(src + 2 * 32 + g4 * 8);
        f32x4 xv5 = *(const f32x4*)(src + 2 * 32 + g4 * 8 + 4);
        float lsum = (xv0[0]+xv0[1]+xv0[2]+xv0[3]) + (xv1[0]+xv1[1]+xv1[2]+xv1[3])
                   + (xv2[0]+xv2[1]+xv2[2]+xv2[3]) + (xv3[0]+xv3[1]+xv3[2]+xv3[3])
                   + (xv4[0]+xv4[1]+xv4[2]+xv4[3]) + (xv5[0]+xv5[1]+xv5[2]+xv5[3]);
        lsum += __shfl_xor(lsum, 16, 64);
        lsum += __shfl_xor(lsum, 32, 64);
        const float mu = lsum * (1.0f / 96.0f);
        f32x4 d0 = xv0 - mu, d1 = xv1 - mu, d2 = xv2 - mu,
              d3 = xv3 - mu, d4 = xv4 - mu, d5 = xv5 - mu;
        float lvv = (d0[0]*d0[0]+d0[1]*d0[1]+d0[2]*d0[2]+d0[3]*d0[3])
                  + (d1[0]*d1[0]+d1[1]*d1[1]+d1[2]*d1[2]+d1[3]*d1[3])
                  + (d2[0]*d2[0]+d2[1]*d2[1]+d2[2]*d2[2]+d2[3]*d2[3])
                  + (d3[0]*d3[0]+d3[1]*d3[1]+d3[2]*d3[2]+d3[3]*d3[3])
                  + (d4[0]*d4[0]+d4[1]*d4[1]+d4[2]*d4[2]+d4[3]*d4[3])
                  + (d5[0]*d5[0]+d5[1]*d5[1]+d5[2]*d5[2]+d5[3]*d5[3]);
        lvv += __shfl_xor(lvv, 16, 64);
        lvv += __shfl_xor(lvv, 32, 64);
        const float rstd = rsqrtf(lvv * (1.0f / 96.0f) + EPS_LN) * live;
#pragma unroll
        for (int ks = 0; ks < 3; ++ks) {
            const f32x4 ea = (ks == 0) ? d0 : (ks == 1) ? d2 : d4;
            const f32x4 eb = (ks == 0) ? d1 : (ks == 1) ? d3 : d5;
            f32x4 ga = *(const f32x4*)(g1 + ks * 32 + g4 * 8);
            f32x4 gb = *(const f32x4*)(g1 + ks * 32 + g4 * 8 + 4);
            f32x4 ba = *(const f32x4*)(b1 + ks * 32 + g4 * 8);
            f32x4 bb = *(const f32x4*)(b1 + ks * 32 + g4 * 8 + 4);
            f32x4 y0 = ea * rstd * ga + ba * live;
            f32x4 y1 = eb * rstd * gb + bb * live;
            xa[ks][0] = pk2(y0[0], y0[1]);
            xa[ks][1] = pk2(y0[2], y0[3]);
            xa[ks][2] = pk2(y1[0], y1[1]);
            xa[ks][3] = pk2(y1[2], y1[3]);
        }
    }

    // ---- QKV: q,k swapped (vector stores); v original (vector token-run stores) ----
#pragma unroll
    for (int sel = 0; sel < 3; ++sel) {
#pragma unroll
        for (int t = 0; t < 6; ++t) {
            const int nt = sel * 6 + t;
            f32x4 acc = {0.f, 0.f, 0.f, 0.f};
            if (sel < 2) {
#pragma unroll
                for (int ks = 0; ks < 3; ++ks) {
                    s16x8 bw = *(const s16x8*)(wqkv + (size_t)(nt * 16 + c16) * 96 + ks * 32 + g4 * 8);
                    acc = __builtin_amdgcn_mfma_f32_16x16x32_bf16(bw, __builtin_bit_cast(s16x8, xa[ks]), acc, 0, 0, 0);
                }
                const int jb = t * 16 + g4 * 4;        // 0..92, 4-run never straddles a head
                const f32x4 b4 = *(const f32x4*)(qkv_b + sel * 96 + jb);
                f32x4 v = acc + b4;
                if (sel == 0) { v[0] *= QSCALE; v[1] *= QSCALE; v[2] *= QSCALE; v[3] *= QSCALE; }
                const int h = jb / 24, db = jb - h * 24;
                u32x2 pkv = { pk2(v[0], v[1]), pk2(v[2], v[3]) };
                const int base = (sel == 0 ? OFF_Q : OFF_K) + h * 3584;
                *(u32x2*)&sm[base + swzQ(mytok, db)] = pkv;
            } else {
#pragma unroll
                for (int ks = 0; ks < 3; ++ks) {
                    s16x8 bw = *(const s16x8*)(wqkv + (size_t)(nt * 16 + c16) * 96 + ks * 32 + g4 * 8);
                    acc = __builtin_amdgcn_mfma_f32_16x16x32_bf16(__builtin_bit_cast(s16x8, xa[ks]), bw, acc, 0, 0, 0);
                }
                const int j96 = t * 16 + c16;
                const float bias = qkv_b[192 + j96];
                const int h = j96 / 24, d = j96 - h * 24;
                const int row0 = mt * 16 + g4 * 4;
                f32x4 v = acc + bias;
                u32x2 pkv = { pk2(v[0], v[1]), pk2(v[2], v[3]) };
                *(u32x2*)&sm[OFF_VT + h * 4096 + swzP(d, row0)] = pkv;
            }
        }
    }
    __syncthreads();                                   // barrier 2 (q/k/vt complete)

    // ---- shift-mask bits for this lane's 28 k-entries (bit nt*4+r) ----
    const int rgq = s_reg[mytok];
    unsigned mbits = 0;
#pragma unroll
    for (int nt = 0; nt < 7; ++nt) {
        const int4 cr = *(const int4*)&s_reg[nt * 16 + g4 * 4];
        mbits |= (unsigned)(cr.x != rgq) << (nt * 4 + 0);
        mbits |= (unsigned)(cr.y != rgq) << (nt * 4 + 1);
        mbits |= (unsigned)(cr.z != rgq) << (nt * 4 + 2);
        mbits |= (unsigned)(cr.w != rgq) << (nt * 4 + 3);
    }

    // ---- 4 heads, barrier-free, token-major ----
    unsigned ogp[4][2][2];
#pragma unroll
    for (int h = 0; h < 4; ++h) {
        const s16x8 aq = *(const s16x8*)&sm[OFF_Q + h * 3584 + swzQ(mytok, g4 * 8)];
        const float* rq = rpbm + h * 16384 + mytok * 128;
        float smr = 0.f;
#pragma unroll
        for (int nt = 0; nt < 7; ++nt) {
            s16x8 ak = *(const s16x8*)&sm[OFF_K + h * 3584 + swzQ(nt * 16 + c16, g4 * 8)];
            f32x4 z = {0.f, 0.f, 0.f, 0.f};
            f32x4 sc = __builtin_amdgcn_mfma_f32_16x16x32_bf16(ak, aq, z, 0, 0, 0);  // swapped: row=k, col=q
            const f32x4 rv = *(const f32x4*)&rq[nt * 16 + g4 * 4];
            float s0 = sc[0] + rv[0] - 100.0f * (float)((mbits >> (nt * 4 + 0)) & 1u);
            float s1 = sc[1] + rv[1] - 100.0f * (float)((mbits >> (nt * 4 + 1)) & 1u);
            float s2 = sc[2] + rv[2] - 100.0f * (float)((mbits >> (nt * 4 + 2)) & 1u);
            float s3 = sc[3] + rv[3] - 100.0f * (float)((mbits >> (nt * 4 + 3)) & 1u);
            const float e0 = __expf(s0), e1 = __expf(s1), e2 = __expf(s2), e3 = __expf(s3);
            smr += (e0 + e1) + (e2 + e3);
            u32x2 pkv = { pk2(e0, e1), pk2(e2, e3) };
            *(u32x2*)&sm[OFF_P + swzP(mytok, nt * 16 + g4 * 4)] = pkv;
        }
        smr += __shfl_xor(smr, 16, 64);
        smr += __shfl_xor(smr, 32, 64);
        const float iq = 1.0f / fmaxf(smr, 1e-30f);
        // PV swapped: A=VT (rows=d), B=P (cols=q tokens) -> lane holds 4 d of own token
#pragma unroll
        for (int dt = 0; dt < 2; ++dt) {
            f32x4 acc = {0.f, 0.f, 0.f, 0.f};
#pragma unroll
            for (int ks = 0; ks < 4; ++ks) {
                s16x8 av = *(const s16x8*)&sm[OFF_VT + h * 4096 + swzP(dt * 16 + c16, ks * 32 + g4 * 8)];
                s16x8 bp = *(const s16x8*)&sm[OFF_P + swzP(mt * 16 + c16, ks * 32 + g4 * 8)];
                acc = __builtin_amdgcn_mfma_f32_16x16x32_bf16(av, bp, acc, 0, 0, 0);
            }
            ogp[h][dt][0] = pk2(acc[0] * iq, acc[1] * iq);
            ogp[h][dt][1] = pk2(acc[2] * iq, acc[3] * iq);
        }
    }

    // ---- O -> P region (own token row, cols 0..95), vector stores ----
#pragma unroll
    for (int h = 0; h < 4; ++h) {
#pragma unroll
        for (int dt = 0; dt < 2; ++dt) {
            const int db = dt * 16 + g4 * 4;
            if (db < 24) {
                u32x2 v = { ogp[h][dt][0], ogp[h][dt][1] };
                *(u32x2*)&sm[OFF_P + swzP(mytok, h * 24 + db)] = v;
            }
        }
    }

    // ---- proj (swapped) + residual -> xl2, vector f32x4 I/O ----
    const int gq = s_gtok[mytok];
#pragma unroll
    for (int nt = 0; nt < 6; ++nt) {
        f32x4 acc = {0.f, 0.f, 0.f, 0.f};
#pragma unroll
        for (int ks = 0; ks < 3; ++ks) {
            s16x8 aw = *(const s16x8*)(wproj + (size_t)(nt * 16 + c16) * 96 + ks * 32 + g4 * 8);
            s16x8 bo = *(const s16x8*)&sm[OFF_P + swzP(mt * 16 + c16, ks * 32 + g4 * 8)];
            acc = __builtin_amdgcn_mfma_f32_16x16x32_bf16(aw, bo, acc, 0, 0, 0);
        }
        if (mytok < 98) {
            const int cb = nt * 16 + g4 * 4;
            const f32x4 pb4 = *(const f32x4*)(proj_b + cb);
            const f32x4 res = *(const f32x4*)(xl + (size_t)gq * C_DIM + cb);
            *(f32x4*)(xl2 + (size_t)gq * C_DIM + cb) = acc + pb4 + res;
        }
    }
}

// ---------------- FFN v3 (round-12 proven): 64-token blocks, weight-fragment reuse ----------------
__global__ __launch_bounds__(256, 3) void k_ffn(
    const float* __restrict__ xl2, float* __restrict__ out,
    const float* __restrict__ g2, const float* __restrict__ b2,
    const u16* __restrict__ w1, const float* __restrict__ fc1_b,
    const u16* __restrict__ w2, const float* __restrict__ fc2_b) {
    __shared__ __align__(16) u16 sg[64 * 384];   // 49152 B
    float* s_res = (float*)sg;                   // [64][97] f32, aliases sg

    const int tid = threadIdx.x;
    const int lane = tid & 63;
    const int wave = tid >> 6;
    const int g4 = lane >> 4, c16 = lane & 15;
    const int mg = wave & 1;
    const int nh = wave >> 1;
    const int t0 = blockIdx.x * 64;

    u32x4 xa[2][3];
#pragma unroll
    for (int g = 0; g < 2; ++g) {
        const int tok = mg * 32 + g * 16 + c16;
        const float* src = xl2 + (size_t)(t0 + tok) * C_DIM;
        f32x4 xv0 = *(const f32x4*)(src + 0 * 32 + g4 * 8);
        f32x4 xv1 = *(const f32x4*)(src + 0 * 32 + g4 * 8 + 4);
        f32x4 xv2 = *(const f32x4*)(src + 1 * 32 + g4 * 8);
        f32x4 xv3 = *(const f32x4*)(src + 1 * 32 + g4 * 8 + 4);
        f32x4 xv4 = *(const f32x4*)(src + 2 * 32 + g4 * 8);
        f32x4 xv5 = *(const f32x4*)(src + 2 * 32 + g4 * 8 + 4);
        float lsum = (xv0[0]+xv0[1]+xv0[2]+xv0[3]) + (xv1[0]+xv1[1]+xv1[2]+xv1[3])
                   + (xv2[0]+xv2[1]+xv2[2]+xv2[3]) + (xv3[0]+xv3[1]+xv3[2]+xv3[3])
                   + (xv4[0]+xv4[1]+xv4[2]+xv4[3]) + (xv5[0]+xv5[1]+xv5[2]+xv5[3]);
        lsum += __shfl_xor(lsum, 16, 64);
        lsum += __shfl_xor(lsum, 32, 64);
        const float mu = lsum * (1.0f / 96.0f);
        f32x4 d0 = xv0 - mu, d1 = xv1 - mu, d2 = xv2 - mu,
              d3 = xv3 - mu, d4 = xv4 - mu, d5 = xv5 - mu;
        float lvv = (d0[0]*d0[0]+d0[1]*d0[1]+d0[2]*d0[2]+d0[3]*d0[3])
                  + (d1[0]*d1[0]+d1[1]*d1[1]+d1[2]*d1[2]+d1[3]*d1[3])
                  + (d2[0]*d2[0]+d2[1]*d2[1]+d2[2]*d2[2]+d2[3]*d2[3])
                  + (d3[0]*d3[0]+d3[1]*d3[1]+d3[2]*d3[2]+d3[3]*d3[3])
                  + (d4[0]*d4[0]+d4[1]*d4[1]+d4[2]*d4[2]+d4[3]*d4[3])
                  + (d5[0]*d5[0]+d5[1]*d5[1]+d5[2]*d5[2]+d5[3]*d5[3]);
        lvv += __shfl_xor(lvv, 16, 64);
        lvv += __shfl_xor(lvv, 32, 64);
        const float rstd = rsqrtf(lvv * (1.0f / 96.0f) + EPS_LN);
#pragma unroll
        for (int ks = 0; ks < 3; ++ks) {
            const f32x4 ea = (ks == 0) ? d0 : (ks == 1) ? d2 : d4;
            const f32x4 eb = (ks == 0) ? d1 : (ks == 1) ? d3 : d5;
            f32x4 ga = *(const f32x4*)(g2 + ks * 32 + g4 * 8);
            f32x4 gb = *(const f32x4*)(g2 + ks * 32 + g4 * 8 + 4);
            f32x4 ba = *(const f32x4*)(b2 + ks * 32 + g4 * 8);
            f32x4 bb = *(const f32x4*)(b2 + ks * 32 + g4 * 8 + 4);
            f32x4 y0 = ea * rstd * ga + ba;
            f32x4 y1 = eb * rstd * gb + bb;
            xa[g][ks][0] = pk2(y0[0], y0[1]);
            xa[g][ks][1] = pk2(y0[2], y0[3]);
            xa[g][ks][2] = pk2(y1[0], y1[1]);
            xa[g][ks][3] = pk2(y1[2], y1[3]);
        }
    }

#pragma unroll 1
    for (int i = 0; i < 12; ++i) {
        const int nt = nh * 12 + i;
        f32x4 acc0 = {0.f, 0.f, 0.f, 0.f};
        f32x4 acc1 = {0.f, 0.f, 0.f, 0.f};
#pragma unroll
        for (int ks = 0; ks < 3; ++ks) {
            s16x8 aw = *(const s16x8*)(w1 + (size_t)(nt * 16 + c16) * 96 + ks * 32 + g4 * 8);
            acc0 = __builtin_amdgcn_mfma_f32_16x16x32_bf16(aw, __builtin_bit_cast(s16x8, xa[0][ks]), acc0, 0, 0, 0);
            acc1 = __builtin_amdgcn_mfma_f32_16x16x32_bf16(aw, __builtin_bit_cast(s16x8, xa[1][ks]), acc1, 0, 0, 0);
        }
        const f32x4 bias = *(const f32x4*)(fc1_b + nt * 16 + g4 * 4);
#pragma unroll
        for (int g = 0; g < 2; ++g) {
            const f32x4 acc = (g == 0) ? acc0 : acc1;
            const int tok = mg * 32 + g * 16 + c16;
            float gv[4];
#pragma unroll
            for (int r = 0; r < 4; ++r) {
                const float v = acc[r] + bias[r];
                gv[r] = 0.5f * v * (1.0f + erff(v * 0.70710678118654752f));
            }
            const int chunk = (2 * nt + (g4 >> 1)) ^ (tok & 15);
            u32x2 pk = { pk2(gv[0], gv[1]), pk2(gv[2], gv[3]) };
            *(u32x2*)&sg[tok * 384 + chunk * 8 + (g4 & 1) * 4] = pk;
        }
    }
    __syncthreads();

    f32x4 facc[3][2];
    const int tokA = mg * 32 + c16;
    const int tokB = tokA + 16;
#pragma unroll 1
    for (int i = 0; i < 3; ++i) {
        const int nt = nh * 3 + i;
        f32x4 a0 = {0.f, 0.f, 0.f, 0.f};
        f32x4 a1 = {0.f, 0.f, 0.f, 0.f};
#pragma unroll
        for (int ks = 0; ks < 12; ++ks) {
            s16x8 aw = *(const s16x8*)(w2 + (size_t)(nt * 16 + c16) * 384 + ks * 32 + g4 * 8);
            s16x8 bg0 = *(const s16x8*)&sg[tokA * 384 + (((ks * 4 + g4) ^ (tokA & 15)) << 3)];
            s16x8 bg1 = *(const s16x8*)&sg[tokB * 384 + (((ks * 4 + g4) ^ (tokB & 15)) << 3)];
            a0 = __builtin_amdgcn_mfma_f32_16x16x32_bf16(aw, bg0, a0, 0, 0, 0);
            a1 = __builtin_amdgcn_mfma_f32_16x16x32_bf16(aw, bg1, a1, 0, 0, 0);
        }
        const f32x4 bias = *(const f32x4*)(fc2_b + nt * 16 + g4 * 4);
        const f32x4 resA = *(const f32x4*)(xl2 + (size_t)(t0 + tokA) * C_DIM + nt * 16 + g4 * 4);
        const f32x4 resB = *(const f32x4*)(xl2 + (size_t)(t0 + tokB) * C_DIM + nt * 16 + g4 * 4);
        facc[i][0] = a0 + bias + resA;
        facc[i][1] = a1 + bias + resB;
    }
    __syncthreads();

#pragma unroll
    for (int i = 0; i < 3; ++i) {
        const int nt = nh * 3 + i;
#pragma unroll
        for (int g = 0; g < 2; ++g) {
            const int tok = mg * 32 + g * 16 + c16;
#pragma unroll
            for (int r = 0; r < 4; ++r)
                s_res[tok * 97 + nt * 16 + g4 * 4 + r] = facc[i][g][r];
        }
    }
    __syncthreads();

    const int bb = t0 / SPATIAL;
    const int sbase = t0 % SPATIAL;
    for (int e = tid; e < 1536; e += 256) {
        const int c = e >> 4, tq = e & 15;
        f32x4 v;
        v[0] = s_res[(tq * 4 + 0) * 97 + c];
        v[1] = s_res[(tq * 4 + 1) * 97 + c];
        v[2] = s_res[(tq * 4 + 2) * 97 + c];
        v[3] = s_res[(tq * 4 + 3) * 97 + c];
        *(f32x4*)&out[((size_t)bb * C_DIM + c) * SPATIAL + sbase + tq * 4] = v;
    }
}

extern "C" void kernel_launch(void* const* d_in, const int* in_sizes, int n_in,
                              void* d_out, int out_size, void* d_ws, size_t ws_size,
                              hipStream_t stream) {
    const float* x      = (const float*)d_in[0];
    const float* g1     = (const float*)d_in[1];
    const float* be1    = (const float*)d_in[2];
    const float* g2     = (const float*)d_in[3];
    const float* be2    = (const float*)d_in[4];
    const float* qkv_w  = (const float*)d_in[5];
    const float* qkv_b  = (const float*)d_in[6];
    const float* proj_w = (const float*)d_in[7];
    const float* proj_b = (const float*)d_in[8];
    const float* rpb    = (const float*)d_in[9];
    const float* fc1_w  = (const float*)d_in[10];
    const float* fc1_b  = (const float*)d_in[11];
    const float* fc2_w  = (const float*)d_in[12];
    const float* fc2_b  = (const float*)d_in[13];
    float* out = (float*)d_out;

    float* xl  = (float*)d_ws;
    float* xl2 = xl + (size_t)NTOK * C_DIM;
    u16* wq = (u16*)(xl2 + (size_t)NTOK * C_DIM);
    u16* wp = wq + 27648;
    u16* w1 = wp + 9216;
    u16* w2 = w1 + 36864;
    float* rpbm = (float*)(w2 + 36864);

    k_prep<<<688, 256, 0, stream>>>(qkv_w, proj_w, fc1_w, fc2_w, rpb, wq, wp, w1, w2, rpbm);
    k_transpose_in<<<dim3(SPATIAL / 32, C_DIM / 32, BATCH), dim3(32, 8), 0, stream>>>(x, xl);
    k_win_attn<<<NWIN_TOT, 448, 0, stream>>>(xl, xl2, g1, be1, wq, qkv_b, wp, proj_b, rpbm);
    k_ffn<<<NTOK / 64, 256, 0, stream>>>(xl2, out, g2, be2, w1, fc1_b, w2, fc2_b);
}